// Round 7
// baseline (524.518 us; speedup 1.0000x reference)
//
#include <hip/hip_runtime.h>

#define BATCH 4096
#define NPATCH 16

typedef __attribute__((ext_vector_type(8)))  short  short8;
typedef __attribute__((ext_vector_type(4)))  float  f32x4;
typedef __attribute__((ext_vector_type(16))) float  f32x16;
typedef unsigned short ushort_t;

__device__ __forceinline__ ushort_t f2bf(float f) {
    union { float f; unsigned u; } x; x.f = f;
    unsigned r = x.u + 0x7FFFu + ((x.u >> 16) & 1u);
    return (ushort_t)(r >> 16);
}

__device__ __forceinline__ void gload_lds16(const void* g, void* l) {
    __builtin_amdgcn_global_load_lds((const __attribute__((address_space(1))) void*)g,
                                     (__attribute__((address_space(3))) void*)l, 16, 0, 0);
}

// ---------------------------------------------------------------------------
// rank: ids_shuffle (ws) + ids_restore -> target (f32, d_out tail)
// ---------------------------------------------------------------------------
__global__ void rank_kernel(const float* __restrict__ noise,
                            int* __restrict__ ids_shuffle,
                            float* __restrict__ target_out) {
    int n = blockIdx.x * 256 + threadIdx.x;
    if (n >= BATCH) return;
    float v[NPATCH];
#pragma unroll
    for (int i = 0; i < NPATCH; i++) v[i] = noise[n * NPATCH + i];
#pragma unroll
    for (int j = 0; j < NPATCH; j++) {
        int r = 0;
#pragma unroll
        for (int i = 0; i < NPATCH; i++)
            if (v[i] < v[j] || (v[i] == v[j] && i < j)) r++;
        ids_shuffle[n * NPATCH + r] = j;
        target_out[n * NPATCH + j] = (float)r;
    }
}

// ---------------------------------------------------------------------------
// patch-shuffle + transpose, f32 NCHW -> bf16 [32h][36wpad][4096n][8icpad]
// ---------------------------------------------------------------------------
__global__ void shuffle_transpose(const float* __restrict__ x,
                                  const int* __restrict__ ids,
                                  ushort_t* __restrict__ y) {
    __shared__ float tile[3][64][33];
    int h = blockIdx.x;
    int n0 = blockIdx.y << 6;
    int t = threadIdx.x;
    int w = t & 31;
    int jrow = (h >> 3) << 2;
#pragma unroll
    for (int r = 0; r < 8; r++) {
        int nl = (t >> 5) + (r << 3);
        int n = n0 + nl;
        int j = jrow + (w >> 3);
        int p = ids[(n << 4) + j];
        int sh = ((p >> 2) << 3) | (h & 7);
        int sw = ((p & 3) << 3) | (w & 7);
#pragma unroll
        for (int c = 0; c < 3; c++)
            tile[c][nl][w] = x[n * 3072 + (c << 10) + (sh << 5) + sw];
    }
    __syncthreads();
    int sub = t >> 6, nl = t & 63;
    int n = n0 + nl;
#pragma unroll
    for (int q = 0; q < 9; q++) {
        int wp = sub * 9 + q;            // 0..35
        int iw = wp - 1;
        ushort_t u[8];
#pragma unroll
        for (int e = 0; e < 8; e++) {
            float v = (e < 3 && iw >= 0 && iw < 32) ? tile[e][nl][iw] : 0.f;
            u[e] = f2bf(v);
        }
        *(uint4*)(y + ((size_t)(h * 36 + wp) * 4096 + n) * 8) = *(const uint4*)u;
    }
}

// ---------------------------------------------------------------------------
// conv weight prep: OIHW f32 -> [oc][k] bf16, k = kh*(KWP*ICP)+kw*ICP+ic
// ---------------------------------------------------------------------------
__global__ void prep_convw(const float* __restrict__ W, ushort_t* __restrict__ WT,
                           int OC, int IC, int ICP, int KWP) {
    int KP = 3 * KWP * ICP;
    int i = blockIdx.x * 256 + threadIdx.x;
    if (i >= OC * KP) return;
    int oc = i / KP, k = i % KP;
    int kh = k / (KWP * ICP);
    int kw = (k / ICP) % KWP;
    int ic = k % ICP;
    ushort_t v = 0;
    if (kw < 3 && ic < IC)
        v = f2bf(W[((oc * IC + ic) * 3 + kh) * 3 + kw]);
    WT[i] = v;
}

// ---------------------------------------------------------------------------
// FC weight prep: [K][N] f32 -> [N][K] bf16
// ---------------------------------------------------------------------------
__global__ void transpose_w(const float* __restrict__ W, ushort_t* __restrict__ WT,
                            int K, int N) {
    __shared__ ushort_t t[32][33];
    int kb = blockIdx.x * 32, nb = blockIdx.y * 32;
    int tx = threadIdx.x & 31, ty = threadIdx.x >> 5;
#pragma unroll
    for (int i = 0; i < 32; i += 8)
        t[ty + i][tx] = f2bf(W[(size_t)(kb + ty + i) * N + nb + tx]);
    __syncthreads();
#pragma unroll
    for (int i = 0; i < 32; i += 8)
        WT[(size_t)(nb + ty + i) * K + kb + tx] = t[tx][ty + i];
}

// fc1 weights with permuted k: WT[n][k'] = W[k][n], k' = hw*128+c, k = c*16+hw
__global__ void transpose_w_fc1(const float* __restrict__ W, ushort_t* __restrict__ WT) {
    __shared__ ushort_t t[32][33];
    int kb = blockIdx.x * 32, nb = blockIdx.y * 32;
    int hw = kb >> 7, c0 = kb & 127;
    int tx = threadIdx.x & 31, ty = threadIdx.x >> 5;
#pragma unroll
    for (int i = 0; i < 32; i += 8)
        t[ty + i][tx] = f2bf(W[(size_t)((c0 + ty + i) * 16 + hw) * 1024 + nb + tx]);
    __syncthreads();
#pragma unroll
    for (int i = 0; i < 32; i += 8)
        WT[(size_t)(nb + ty + i) * 2048 + kb + tx] = t[tx][ty + i];
}

// ---------------------------------------------------------------------------
// conv1: 3->32, 3x3 SAME + relu + pool, mfma 32x32x16 bf16.
// X: [32][36][4096][8] bf16 (padded). WT: [32oc][96] (k = kh*32+kw*8+ic).
// ---------------------------------------------------------------------------
__global__ __launch_bounds__(256, 4)
void conv1_mfma(const ushort_t* __restrict__ X, const ushort_t* __restrict__ WT,
                const float* __restrict__ bias, ushort_t* __restrict__ Y) {
    const int tid = threadIdx.x;
    const int wid = tid >> 6, lane = tid & 63;
    const int nl = lane & 31, kc = lane >> 5;
    const int pos = blockIdx.x;
    const int ph = pos >> 4, pw = pos & 15;
    const int n = (blockIdx.z * 4 + wid) * 32 + nl;

    f32x16 acc[4];
#pragma unroll
    for (int p = 0; p < 4; ++p)
#pragma unroll
        for (int r = 0; r < 16; ++r) acc[p][r] = 0.f;

    const ushort_t* wp_ = WT + nl * 96 + kc * 8;
#pragma unroll
    for (int s = 0; s < 6; ++s) {
        int kh = s >> 1;
        int kw = ((s & 1) << 1) + kc;
        short8 af = *(const short8*)(wp_ + s * 16);
        short8 bf[4];
#pragma unroll
        for (int p = 0; p < 4; ++p) {
            int pr = p >> 1, pc = p & 1;
            int ih = 2 * ph + pr - 1 + kh;
            int wpad = 2 * pw + pc + kw;
            short8 b = {};
            if ((unsigned)ih < 32u)
                b = *(const short8*)(X + ((size_t)(ih * 36 + wpad) * 4096 + n) * 8);
            bf[p] = b;
        }
#pragma unroll
        for (int p = 0; p < 4; ++p)
            acc[p] = __builtin_amdgcn_mfma_f32_32x32x16_bf16(af, bf[p], acc[p], 0, 0, 0);
    }
#pragma unroll
    for (int g = 0; g < 4; ++g) {
        ushort_t u[4];
        int ocb = 8 * g + 4 * kc;
#pragma unroll
        for (int j = 0; j < 4; ++j) {
            int reg = 4 * g + j;
            float mx = fmaxf(fmaxf(acc[0][reg], acc[1][reg]), fmaxf(acc[2][reg], acc[3][reg]));
            u[j] = f2bf(fmaxf(mx + bias[ocb + j], 0.f));
        }
        *(uint2*)(Y + ((size_t)(ph * 16 + pw) * 4096 + n) * 32 + ocb) = *(const uint2*)u;
    }
}

// ---------------------------------------------------------------------------
// conv2/3: implicit GEMM + relu + pool, oc-block 32 (acc=64 regs -> 16 waves/CU).
// X: [H][H][4096][IC] bf16. WT: [OC][9*IC] (k = tap*IC+ic).
// FC_EPI: write act3[n][2048] with k' = (ph*4+pw)*128 + oc.
// ---------------------------------------------------------------------------
template <int IC, int H, int OCT, bool FC_EPI>
__global__ __launch_bounds__(256, 4)
void conv_mfma(const ushort_t* __restrict__ X, const ushort_t* __restrict__ WT,
               const float* __restrict__ bias, ushort_t* __restrict__ Y) {
    constexpr int K = 9 * IC, NS = K / 16, SPT = IC / 16, PW = H / 2;
    const int tid = threadIdx.x;
    const int wid = tid >> 6, lane = tid & 63;
    const int nl = lane & 31, kc = lane >> 5;
    const int pos = blockIdx.x;
    const int ph = pos / PW, pw = pos % PW;
    const int ocg = blockIdx.y;
    const int n = (blockIdx.z * 4 + wid) * 32 + nl;

    f32x16 acc[4];
#pragma unroll
    for (int p = 0; p < 4; ++p)
#pragma unroll
        for (int r = 0; r < 16; ++r) acc[p][r] = 0.f;

    const ushort_t* wpA = WT + (size_t)(ocg * 32 + nl) * K + kc * 8;
#pragma unroll 2
    for (int s = 0; s < NS; ++s) {
        int tap = s / SPT;
        int icb = (s % SPT) * 16 + kc * 8;
        int kh = tap / 3, kw = tap % 3;
        short8 af = *(const short8*)(wpA + s * 16);
        short8 bf[4];
#pragma unroll
        for (int p = 0; p < 4; ++p) {
            int pr = p >> 1, pc = p & 1;
            int ih = 2 * ph + pr - 1 + kh;
            int iw = 2 * pw + pc - 1 + kw;
            short8 b = {};
            if ((unsigned)ih < (unsigned)H && (unsigned)iw < (unsigned)H)
                b = *(const short8*)(X + ((size_t)(ih * H + iw) * 4096 + n) * IC + icb);
            bf[p] = b;
        }
#pragma unroll
        for (int p = 0; p < 4; ++p)
            acc[p] = __builtin_amdgcn_mfma_f32_32x32x16_bf16(af, bf[p], acc[p], 0, 0, 0);
    }
#pragma unroll
    for (int g = 0; g < 4; ++g) {
        ushort_t u[4];
        int ocl = 8 * g + 4 * kc;
        int oc  = ocg * 32 + ocl;
#pragma unroll
        for (int j = 0; j < 4; ++j) {
            int reg = 4 * g + j;
            float mx = fmaxf(fmaxf(acc[0][reg], acc[1][reg]),
                             fmaxf(acc[2][reg], acc[3][reg]));
            u[j] = f2bf(fmaxf(mx + bias[oc + j], 0.f));
        }
        if (FC_EPI)
            *(uint2*)(Y + (size_t)n * 2048 + (ph * 4 + pw) * 128 + oc) = *(const uint2*)u;
        else
            *(uint2*)(Y + ((size_t)(ph * PW + pw) * 4096 + n) * OCT + oc) = *(const uint2*)u;
    }
}

// ---------------------------------------------------------------------------
// FC GEMM: C[M][N] = act(A[M][K] @ W + b), BT[N][K]. 128x128 tile, BK=64,
// 4 waves, mfma 16x16x32, global_load_lds + stage_rc XOR swizzle.
// ---------------------------------------------------------------------------
template <bool RELU, bool F32OUT>
__global__ __launch_bounds__(256, 2)
void fc_mfma(const ushort_t* __restrict__ A, const ushort_t* __restrict__ BT,
             const float* __restrict__ bias, void* __restrict__ Cout,
             int M, int N, int K) {
    __shared__ ushort_t As[128 * 64];
    __shared__ ushort_t Bs[128 * 64];
    const int tid = threadIdx.x;
    const int wid = tid >> 6, lane = tid & 63;
    const int wr = wid >> 1, wc = wid & 1;
    const int tm = blockIdx.y * 128, tn = blockIdx.x * 128;
    const int l15 = lane & 15, l4 = lane >> 4;

    f32x4 acc[4][4];
#pragma unroll
    for (int i = 0; i < 4; ++i)
#pragma unroll
        for (int j = 0; j < 4; ++j)
#pragma unroll
            for (int r = 0; r < 4; ++r) acc[i][j][r] = 0.f;

    for (int k0 = 0; k0 < K; k0 += 64) {
        __syncthreads();
#pragma unroll
        for (int pass = 0; pass < 4; ++pass) {
            int idx = pass * 256 + tid;
            int m = idx >> 3, ss = idx & 7;
            int cc = ss ^ (m & 7);
            gload_lds16(A  + (size_t)(tm + m) * K + k0 + cc * 8,
                        &As[(pass * 256 + wid * 64) * 8]);
            gload_lds16(BT + (size_t)(tn + m) * K + k0 + cc * 8,
                        &Bs[(pass * 256 + wid * 64) * 8]);
        }
        __syncthreads();
#pragma unroll
        for (int kk = 0; kk < 2; ++kk) {
            short8 af[4], bfr[4];
            int c = kk * 4 + l4;
#pragma unroll
            for (int i = 0; i < 4; ++i) {
                int m = wr * 64 + i * 16 + l15;
                af[i]  = *(const short8*)(As + m * 64 + (c ^ (m & 7)) * 8);
                int nn = wc * 64 + i * 16 + l15;
                bfr[i] = *(const short8*)(Bs + nn * 64 + (c ^ (nn & 7)) * 8);
            }
#pragma unroll
            for (int i = 0; i < 4; ++i)
#pragma unroll
                for (int j = 0; j < 4; ++j)
                    acc[i][j] = __builtin_amdgcn_mfma_f32_16x16x32_bf16(
                        af[i], bfr[j], acc[i][j], 0, 0, 0);
        }
    }
#pragma unroll
    for (int i = 0; i < 4; ++i) {
        int row = tm + wr * 64 + i * 16 + l4 * 4;
#pragma unroll
        for (int j = 0; j < 4; ++j) {
            int col = tn + wc * 64 + j * 16 + l15;
            float bv = bias[col];
#pragma unroll
            for (int r = 0; r < 4; ++r) {
                float v = acc[i][j][r] + bv;
                if (RELU) v = fmaxf(v, 0.f);
                if (F32OUT)
                    ((float*)Cout)[(size_t)(row + r) * N + col] = v;
                else
                    ((ushort_t*)Cout)[(size_t)(row + r) * N + col] = f2bf(v);
            }
        }
    }
}

// ---------------------------------------------------------------------------
extern "C" void kernel_launch(void* const* d_in, const int* in_sizes, int n_in,
                              void* d_out, int out_size, void* d_ws, size_t ws_size,
                              hipStream_t stream) {
    const float* x     = (const float*)d_in[0];
    const float* noise = (const float*)d_in[1];
    const float* c1w = (const float*)d_in[2];  const float* c1b = (const float*)d_in[3];
    const float* c2w = (const float*)d_in[4];  const float* c2b = (const float*)d_in[5];
    const float* c3w = (const float*)d_in[6];  const float* c3b = (const float*)d_in[7];
    const float* f1w = (const float*)d_in[8];  const float* f1b = (const float*)d_in[9];
    const float* f2w = (const float*)d_in[10]; const float* f2b = (const float*)d_in[11];
    const float* f3w = (const float*)d_in[12]; const float* f3b = (const float*)d_in[13];
    const float* f4w = (const float*)d_in[14]; const float* f4b = (const float*)d_in[15];
    const float* f5w = (const float*)d_in[16]; const float* f5b = (const float*)d_in[17];
    float* out = (float*)d_out;

    char* ws = (char*)d_ws;
    const size_t MB = 1ull << 20;
    int*      ids  = (int*)ws;                               // 256 KB
    ushort_t* wc1  = (ushort_t*)(ws + 1 * MB);               // 6 KB
    ushort_t* wc2  = (ushort_t*)(ws + 1 * MB + 64 * 1024);   // 36 KB
    ushort_t* wc3  = (ushort_t*)(ws + 1 * MB + 128 * 1024);  // 144 KB
    ushort_t* wf1  = (ushort_t*)(ws + 2 * MB);               // 4 MB
    ushort_t* wf2  = (ushort_t*)(ws + 6 * MB);               // 2 MB
    ushort_t* wf3  = (ushort_t*)(ws + 8 * MB);               // 2 MB
    ushort_t* wf4  = (ushort_t*)(ws + 10 * MB);              // 2 MB
    ushort_t* wf5  = (ushort_t*)(ws + 12 * MB);              // 0.5 MB
    ushort_t* act0 = (ushort_t*)(ws + 13 * MB);              // 75.5 MB [32][36][4096][8]
    ushort_t* act1 = (ushort_t*)(ws + 89 * MB);              // 64 MB  [16][16][4096][32]
    ushort_t* act2 = (ushort_t*)(ws + 153 * MB);             // 32 MB  [8][8][4096][64]
    ushort_t* act3 = (ushort_t*)(ws + 185 * MB);             // 16 MB  [4096][2048]
    ushort_t* fcb1 = (ushort_t*)(ws + 201 * MB);             // 8 MB
    ushort_t* fcb2 = (ushort_t*)(ws + 209 * MB);             // 8 MB

    // weight preps
    prep_convw<<<(32 * 96 + 255) / 256, 256, 0, stream>>>(c1w, wc1, 32, 3, 8, 4);
    prep_convw<<<(64 * 288 + 255) / 256, 256, 0, stream>>>(c2w, wc2, 64, 32, 32, 3);
    prep_convw<<<(128 * 576 + 255) / 256, 256, 0, stream>>>(c3w, wc3, 128, 64, 64, 3);
    transpose_w_fc1<<<dim3(64, 32), 256, 0, stream>>>(f1w, wf1);
    transpose_w<<<dim3(32, 32), 256, 0, stream>>>(f2w, wf2, 1024, 1024);
    transpose_w<<<dim3(32, 32), 256, 0, stream>>>(f3w, wf3, 1024, 1024);
    transpose_w<<<dim3(32, 32), 256, 0, stream>>>(f4w, wf4, 1024, 1024);
    transpose_w<<<dim3(32, 8),  256, 0, stream>>>(f5w, wf5, 1024, 256);

    // shuffle + target
    rank_kernel<<<BATCH / 256, 256, 0, stream>>>(noise, ids, out + (size_t)BATCH * 256);
    shuffle_transpose<<<dim3(32, 64), 256, 0, stream>>>(x, ids, act0);

    // convs (channel-innermost implicit GEMM, fused relu+pool, oc-block 32)
    conv1_mfma<<<dim3(256, 1, 32), 256, 0, stream>>>(act0, wc1, c1b, act1);
    conv_mfma<32, 16, 64,  false><<<dim3(64, 2, 32), 256, 0, stream>>>(act1, wc2, c2b, act2);
    conv_mfma<64, 8,  128, true ><<<dim3(16, 4, 32), 256, 0, stream>>>(act2, wc3, c3b, act3);

    // FC chain
    fc_mfma<true,  false><<<dim3(8, 32), 256, 0, stream>>>(act3, wf1, f1b, fcb1, BATCH, 1024, 2048);
    fc_mfma<true,  false><<<dim3(8, 32), 256, 0, stream>>>(fcb1, wf2, f2b, fcb2, BATCH, 1024, 1024);
    fc_mfma<true,  false><<<dim3(8, 32), 256, 0, stream>>>(fcb2, wf3, f3b, fcb1, BATCH, 1024, 1024);
    fc_mfma<true,  false><<<dim3(8, 32), 256, 0, stream>>>(fcb1, wf4, f4b, fcb2, BATCH, 1024, 1024);
    fc_mfma<false, true ><<<dim3(2, 32), 256, 0, stream>>>(fcb2, wf5, f5b, out, BATCH, 256, 1024);
}

// Round 8
// 414.248 us; speedup vs baseline: 1.2662x; 1.2662x over previous
//
#include <hip/hip_runtime.h>

#define BATCH 4096
#define NPATCH 16

typedef __attribute__((ext_vector_type(8)))  short  short8;
typedef __attribute__((ext_vector_type(4)))  float  f32x4;
typedef __attribute__((ext_vector_type(16))) float  f32x16;
typedef unsigned short ushort_t;

__device__ __forceinline__ ushort_t f2bf(float f) {
    union { float f; unsigned u; } x; x.f = f;
    unsigned r = x.u + 0x7FFFu + ((x.u >> 16) & 1u);
    return (ushort_t)(r >> 16);
}

__device__ __forceinline__ void gload_lds16(const void* g, void* l) {
    __builtin_amdgcn_global_load_lds((const __attribute__((address_space(1))) void*)g,
                                     (__attribute__((address_space(3))) void*)l, 16, 0, 0);
}

// ---------------------------------------------------------------------------
// rank: ids_shuffle (ws) + ids_restore -> target (f32, d_out tail)
// ---------------------------------------------------------------------------
__global__ void rank_kernel(const float* __restrict__ noise,
                            int* __restrict__ ids_shuffle,
                            float* __restrict__ target_out) {
    int n = blockIdx.x * 256 + threadIdx.x;
    if (n >= BATCH) return;
    float v[NPATCH];
#pragma unroll
    for (int i = 0; i < NPATCH; i++) v[i] = noise[n * NPATCH + i];
#pragma unroll
    for (int j = 0; j < NPATCH; j++) {
        int r = 0;
#pragma unroll
        for (int i = 0; i < NPATCH; i++)
            if (v[i] < v[j] || (v[i] == v[j] && i < j)) r++;
        ids_shuffle[n * NPATCH + r] = j;
        target_out[n * NPATCH + j] = (float)r;
    }
}

// ---------------------------------------------------------------------------
// patch-shuffle + transpose, f32 NCHW -> bf16 [32h][36wpad][4096n][8icpad]
// ---------------------------------------------------------------------------
__global__ void shuffle_transpose(const float* __restrict__ x,
                                  const int* __restrict__ ids,
                                  ushort_t* __restrict__ y) {
    __shared__ float tile[3][64][33];
    int h = blockIdx.x;
    int n0 = blockIdx.y << 6;
    int t = threadIdx.x;
    int w = t & 31;
    int jrow = (h >> 3) << 2;
#pragma unroll
    for (int r = 0; r < 8; r++) {
        int nl = (t >> 5) + (r << 3);
        int n = n0 + nl;
        int j = jrow + (w >> 3);
        int p = ids[(n << 4) + j];
        int sh = ((p >> 2) << 3) | (h & 7);
        int sw = ((p & 3) << 3) | (w & 7);
#pragma unroll
        for (int c = 0; c < 3; c++)
            tile[c][nl][w] = x[n * 3072 + (c << 10) + (sh << 5) + sw];
    }
    __syncthreads();
    int sub = t >> 6, nl = t & 63;
    int n = n0 + nl;
#pragma unroll
    for (int q = 0; q < 9; q++) {
        int wp = sub * 9 + q;            // 0..35
        int iw = wp - 1;
        ushort_t u[8];
#pragma unroll
        for (int e = 0; e < 8; e++) {
            float v = (e < 3 && iw >= 0 && iw < 32) ? tile[e][nl][iw] : 0.f;
            u[e] = f2bf(v);
        }
        *(uint4*)(y + ((size_t)(h * 36 + wp) * 4096 + n) * 8) = *(const uint4*)u;
    }
}

// ---------------------------------------------------------------------------
// conv weight prep: OIHW f32 -> [oc][k] bf16, k = kh*(KWP*ICP)+kw*ICP+ic
// ---------------------------------------------------------------------------
__global__ void prep_convw(const float* __restrict__ W, ushort_t* __restrict__ WT,
                           int OC, int IC, int ICP, int KWP) {
    int KP = 3 * KWP * ICP;
    int i = blockIdx.x * 256 + threadIdx.x;
    if (i >= OC * KP) return;
    int oc = i / KP, k = i % KP;
    int kh = k / (KWP * ICP);
    int kw = (k / ICP) % KWP;
    int ic = k % ICP;
    ushort_t v = 0;
    if (kw < 3 && ic < IC)
        v = f2bf(W[((oc * IC + ic) * 3 + kh) * 3 + kw]);
    WT[i] = v;
}

// ---------------------------------------------------------------------------
// FC weight prep: [K][N] f32 -> [N][K] bf16
// ---------------------------------------------------------------------------
__global__ void transpose_w(const float* __restrict__ W, ushort_t* __restrict__ WT,
                            int K, int N) {
    __shared__ ushort_t t[32][33];
    int kb = blockIdx.x * 32, nb = blockIdx.y * 32;
    int tx = threadIdx.x & 31, ty = threadIdx.x >> 5;
#pragma unroll
    for (int i = 0; i < 32; i += 8)
        t[ty + i][tx] = f2bf(W[(size_t)(kb + ty + i) * N + nb + tx]);
    __syncthreads();
#pragma unroll
    for (int i = 0; i < 32; i += 8)
        WT[(size_t)(nb + ty + i) * K + kb + tx] = t[tx][ty + i];
}

// fc1 weights with permuted k: WT[n][k'] = W[k][n], k' = hw*128+c, k = c*16+hw
__global__ void transpose_w_fc1(const float* __restrict__ W, ushort_t* __restrict__ WT) {
    __shared__ ushort_t t[32][33];
    int kb = blockIdx.x * 32, nb = blockIdx.y * 32;
    int hw = kb >> 7, c0 = kb & 127;
    int tx = threadIdx.x & 31, ty = threadIdx.x >> 5;
#pragma unroll
    for (int i = 0; i < 32; i += 8)
        t[ty + i][tx] = f2bf(W[(size_t)((c0 + ty + i) * 16 + hw) * 1024 + nb + tx]);
    __syncthreads();
#pragma unroll
    for (int i = 0; i < 32; i += 8)
        WT[(size_t)(nb + ty + i) * 2048 + kb + tx] = t[tx][ty + i];
}

// ---------------------------------------------------------------------------
// conv1: 3->32, 3x3 SAME + relu + pool, mfma 32x32x16 bf16. (round-6 form)
// X: [32][36][4096][8] bf16 (padded). WT: [32oc][96] (k = kh*32+kw*8+ic).
// ---------------------------------------------------------------------------
__global__ __launch_bounds__(256, 4)
void conv1_mfma(const ushort_t* __restrict__ X, const ushort_t* __restrict__ WT,
                const float* __restrict__ bias, ushort_t* __restrict__ Y) {
    const int tid = threadIdx.x;
    const int wid = tid >> 6, lane = tid & 63;
    const int nl = lane & 31, kc = lane >> 5;
    const int pos = blockIdx.x;
    const int ph = pos >> 4, pw = pos & 15;
    const int n = (blockIdx.z * 4 + wid) * 32 + nl;

    f32x16 acc[4];
#pragma unroll
    for (int p = 0; p < 4; ++p)
#pragma unroll
        for (int r = 0; r < 16; ++r) acc[p][r] = 0.f;

    const ushort_t* wp_ = WT + nl * 96 + kc * 8;
#pragma unroll
    for (int s = 0; s < 6; ++s) {
        int kh = s >> 1;
        int kw = ((s & 1) << 1) + kc;
        short8 af = *(const short8*)(wp_ + s * 16);
        short8 bf[4];
#pragma unroll
        for (int p = 0; p < 4; ++p) {
            int pr = p >> 1, pc = p & 1;
            int ih = 2 * ph + pr - 1 + kh;
            int wpad = 2 * pw + pc + kw;
            short8 b = {};
            if ((unsigned)ih < 32u)
                b = *(const short8*)(X + ((size_t)(ih * 36 + wpad) * 4096 + n) * 8);
            bf[p] = b;
        }
#pragma unroll
        for (int p = 0; p < 4; ++p)
            acc[p] = __builtin_amdgcn_mfma_f32_32x32x16_bf16(af, bf[p], acc[p], 0, 0, 0);
    }
#pragma unroll
    for (int g = 0; g < 4; ++g) {
        ushort_t u[4];
        int ocb = 8 * g + 4 * kc;
#pragma unroll
        for (int j = 0; j < 4; ++j) {
            int reg = 4 * g + j;
            float mx = fmaxf(fmaxf(acc[0][reg], acc[1][reg]), fmaxf(acc[2][reg], acc[3][reg]));
            u[j] = f2bf(fmaxf(mx + bias[ocb + j], 0.f));
        }
        *(uint2*)(Y + ((size_t)(ph * 16 + pw) * 4096 + n) * 32 + ocb) = *(const uint2*)u;
    }
}

// ---------------------------------------------------------------------------
// conv2/3 as LDS-staged GEMM + pool-max. One block = one pooled position x
// 128-n tile x all OC. Loops 4 conv positions (running max) x 9 taps.
// Per tap: stage As=weights[OC][IC], Bs=acts[128][IC] via global_load_lds
// (both contiguous slabs), XOR-swizzled; mfma 16x16x32 from LDS.
// A-operand = weights (C rows = oc) -> packed uint2 oc-epilogue.
// OOB taps skipped (block-uniform; zero contribution).
// ---------------------------------------------------------------------------
template <int IC, int H, int OC, bool FC_EPI, int MINB>
__global__ __launch_bounds__(256, MINB)
void conv_gemm(const ushort_t* __restrict__ X, const ushort_t* __restrict__ WT,
               const float* __restrict__ bias, ushort_t* __restrict__ Y) {
    constexpr int PW = H / 2;
    constexpr int K  = 9 * IC;
    constexpr int CH = IC / 8;          // 16B chunks per row
    constexpr int CM = CH - 1;          // swizzle mask
    constexpr int KK = IC / 32;         // mfma k-steps per tap
    constexpr int WM = (OC == 128) ? 2 : 1;   // waves on oc dim
    constexpr int WN = 4 / WM;                // waves on n dim
    constexpr int WTM = OC / WM / 16;         // 4
    constexpr int WTN = 128 / WN / 16;        // conv3:4, conv2:2
    constexpr int APASS = OC * CH / 256;      // conv3:4, conv2:1
    constexpr int BPASS = 128 * CH / 256;     // conv3:4, conv2:2

    __shared__ ushort_t As[OC * IC];
    __shared__ ushort_t Bs[128 * IC];
    const int tid = threadIdx.x;
    const int wid = tid >> 6, lane = tid & 63;
    const int wm = wid / WN, wn = wid % WN;
    const int l15 = lane & 15, l4 = lane >> 4;
    const int ph = blockIdx.x / PW, pw = blockIdx.x % PW;
    const int n0 = blockIdx.y * 128;

    f32x4 acc[WTM][WTN], mx[WTM][WTN];

    for (int p = 0; p < 4; ++p) {
#pragma unroll
        for (int i = 0; i < WTM; ++i)
#pragma unroll
            for (int j = 0; j < WTN; ++j)
#pragma unroll
                for (int r = 0; r < 4; ++r) acc[i][j][r] = 0.f;
        const int pr = p >> 1, pc = p & 1;
        for (int t = 0; t < 9; ++t) {
            const int kh = t / 3, kw = t % 3;
            const int ih = 2 * ph + pr - 1 + kh;
            const int iw = 2 * pw + pc - 1 + kw;
            if ((unsigned)ih >= (unsigned)H || (unsigned)iw >= (unsigned)H) continue;
            __syncthreads();   // prior tap's LDS reads complete
            const ushort_t* bsrc = X + (size_t)(ih * H + iw) * 4096 * IC + (size_t)n0 * IC;
#pragma unroll
            for (int pass = 0; pass < APASS; ++pass) {
                int idx = pass * 256 + tid;
                int m = idx / CH, ss = idx % CH;
                int cc = ss ^ (m & CM);
                gload_lds16(WT + (size_t)m * K + t * IC + cc * 8,
                            &As[(pass * 256 + wid * 64) * 8]);
            }
#pragma unroll
            for (int pass = 0; pass < BPASS; ++pass) {
                int idx = pass * 256 + tid;
                int m = idx / CH, ss = idx % CH;
                int cc = ss ^ (m & CM);
                gload_lds16(bsrc + (size_t)m * IC + cc * 8,
                            &Bs[(pass * 256 + wid * 64) * 8]);
            }
            __syncthreads();   // staging complete
#pragma unroll
            for (int kk = 0; kk < KK; ++kk) {
                short8 af[WTM], bf[WTN];
                int c = kk * 4 + l4;
#pragma unroll
                for (int i = 0; i < WTM; ++i) {
                    int m = wm * (WTM * 16) + i * 16 + l15;
                    af[i] = *(const short8*)(As + m * IC + ((c ^ (m & CM)) * 8));
                }
#pragma unroll
                for (int j = 0; j < WTN; ++j) {
                    int m = wn * (WTN * 16) + j * 16 + l15;
                    bf[j] = *(const short8*)(Bs + m * IC + ((c ^ (m & CM)) * 8));
                }
#pragma unroll
                for (int i = 0; i < WTM; ++i)
#pragma unroll
                    for (int j = 0; j < WTN; ++j)
                        acc[i][j] = __builtin_amdgcn_mfma_f32_16x16x32_bf16(
                            af[i], bf[j], acc[i][j], 0, 0, 0);
            }
        }
#pragma unroll
        for (int i = 0; i < WTM; ++i)
#pragma unroll
            for (int j = 0; j < WTN; ++j)
#pragma unroll
                for (int r = 0; r < 4; ++r)
                    mx[i][j][r] = (p == 0) ? acc[i][j][r]
                                           : fmaxf(mx[i][j][r], acc[i][j][r]);
    }

    // C/D 16x16: row(=oc) = l4*4 + r (+i*16 + wave), col(=n) = l15 (+j*16 + wave)
#pragma unroll
    for (int i = 0; i < WTM; ++i) {
        int oc_l = wm * (WTM * 16) + i * 16 + l4 * 4;
#pragma unroll
        for (int j = 0; j < WTN; ++j) {
            int n = n0 + wn * (WTN * 16) + j * 16 + l15;
            ushort_t u[4];
#pragma unroll
            for (int r = 0; r < 4; ++r)
                u[r] = f2bf(fmaxf(mx[i][j][r] + bias[oc_l + r], 0.f));
            if (FC_EPI)
                *(uint2*)(Y + (size_t)n * 2048 + (ph * 4 + pw) * 128 + oc_l) = *(const uint2*)u;
            else
                *(uint2*)(Y + ((size_t)(ph * PW + pw) * 4096 + n) * OC + oc_l) = *(const uint2*)u;
        }
    }
}

// ---------------------------------------------------------------------------
// FC GEMM: C[M][N] = act(A[M][K] @ W + b), BT[N][K]. 128x128 tile, BK=64,
// 4 waves, mfma 16x16x32, global_load_lds + stage_rc XOR swizzle.
// ---------------------------------------------------------------------------
template <bool RELU, bool F32OUT>
__global__ __launch_bounds__(256, 2)
void fc_mfma(const ushort_t* __restrict__ A, const ushort_t* __restrict__ BT,
             const float* __restrict__ bias, void* __restrict__ Cout,
             int M, int N, int K) {
    __shared__ ushort_t As[128 * 64];
    __shared__ ushort_t Bs[128 * 64];
    const int tid = threadIdx.x;
    const int wid = tid >> 6, lane = tid & 63;
    const int wr = wid >> 1, wc = wid & 1;
    const int tm = blockIdx.y * 128, tn = blockIdx.x * 128;
    const int l15 = lane & 15, l4 = lane >> 4;

    f32x4 acc[4][4];
#pragma unroll
    for (int i = 0; i < 4; ++i)
#pragma unroll
        for (int j = 0; j < 4; ++j)
#pragma unroll
            for (int r = 0; r < 4; ++r) acc[i][j][r] = 0.f;

    for (int k0 = 0; k0 < K; k0 += 64) {
        __syncthreads();
#pragma unroll
        for (int pass = 0; pass < 4; ++pass) {
            int idx = pass * 256 + tid;
            int m = idx >> 3, ss = idx & 7;
            int cc = ss ^ (m & 7);
            gload_lds16(A  + (size_t)(tm + m) * K + k0 + cc * 8,
                        &As[(pass * 256 + wid * 64) * 8]);
            gload_lds16(BT + (size_t)(tn + m) * K + k0 + cc * 8,
                        &Bs[(pass * 256 + wid * 64) * 8]);
        }
        __syncthreads();
#pragma unroll
        for (int kk = 0; kk < 2; ++kk) {
            short8 af[4], bfr[4];
            int c = kk * 4 + l4;
#pragma unroll
            for (int i = 0; i < 4; ++i) {
                int m = wr * 64 + i * 16 + l15;
                af[i]  = *(const short8*)(As + m * 64 + (c ^ (m & 7)) * 8);
                int nn = wc * 64 + i * 16 + l15;
                bfr[i] = *(const short8*)(Bs + nn * 64 + (c ^ (nn & 7)) * 8);
            }
#pragma unroll
            for (int i = 0; i < 4; ++i)
#pragma unroll
                for (int j = 0; j < 4; ++j)
                    acc[i][j] = __builtin_amdgcn_mfma_f32_16x16x32_bf16(
                        af[i], bfr[j], acc[i][j], 0, 0, 0);
        }
    }
#pragma unroll
    for (int i = 0; i < 4; ++i) {
        int row = tm + wr * 64 + i * 16 + l4 * 4;
#pragma unroll
        for (int j = 0; j < 4; ++j) {
            int col = tn + wc * 64 + j * 16 + l15;
            float bv = bias[col];
#pragma unroll
            for (int r = 0; r < 4; ++r) {
                float v = acc[i][j][r] + bv;
                if (RELU) v = fmaxf(v, 0.f);
                if (F32OUT)
                    ((float*)Cout)[(size_t)(row + r) * N + col] = v;
                else
                    ((ushort_t*)Cout)[(size_t)(row + r) * N + col] = f2bf(v);
            }
        }
    }
}

// ---------------------------------------------------------------------------
extern "C" void kernel_launch(void* const* d_in, const int* in_sizes, int n_in,
                              void* d_out, int out_size, void* d_ws, size_t ws_size,
                              hipStream_t stream) {
    const float* x     = (const float*)d_in[0];
    const float* noise = (const float*)d_in[1];
    const float* c1w = (const float*)d_in[2];  const float* c1b = (const float*)d_in[3];
    const float* c2w = (const float*)d_in[4];  const float* c2b = (const float*)d_in[5];
    const float* c3w = (const float*)d_in[6];  const float* c3b = (const float*)d_in[7];
    const float* f1w = (const float*)d_in[8];  const float* f1b = (const float*)d_in[9];
    const float* f2w = (const float*)d_in[10]; const float* f2b = (const float*)d_in[11];
    const float* f3w = (const float*)d_in[12]; const float* f3b = (const float*)d_in[13];
    const float* f4w = (const float*)d_in[14]; const float* f4b = (const float*)d_in[15];
    const float* f5w = (const float*)d_in[16]; const float* f5b = (const float*)d_in[17];
    float* out = (float*)d_out;

    char* ws = (char*)d_ws;
    const size_t MB = 1ull << 20;
    int*      ids  = (int*)ws;                               // 256 KB
    ushort_t* wc1  = (ushort_t*)(ws + 1 * MB);               // 6 KB
    ushort_t* wc2  = (ushort_t*)(ws + 1 * MB + 64 * 1024);   // 36 KB
    ushort_t* wc3  = (ushort_t*)(ws + 1 * MB + 128 * 1024);  // 144 KB
    ushort_t* wf1  = (ushort_t*)(ws + 2 * MB);               // 4 MB
    ushort_t* wf2  = (ushort_t*)(ws + 6 * MB);               // 2 MB
    ushort_t* wf3  = (ushort_t*)(ws + 8 * MB);               // 2 MB
    ushort_t* wf4  = (ushort_t*)(ws + 10 * MB);              // 2 MB
    ushort_t* wf5  = (ushort_t*)(ws + 12 * MB);              // 0.5 MB
    ushort_t* act0 = (ushort_t*)(ws + 13 * MB);              // 75.5 MB [32][36][4096][8]
    ushort_t* act1 = (ushort_t*)(ws + 89 * MB);              // 64 MB  [16][16][4096][32]
    ushort_t* act2 = (ushort_t*)(ws + 153 * MB);             // 32 MB  [8][8][4096][64]
    ushort_t* act3 = (ushort_t*)(ws + 185 * MB);             // 16 MB  [4096][2048]
    ushort_t* fcb1 = (ushort_t*)(ws + 201 * MB);             // 8 MB
    ushort_t* fcb2 = (ushort_t*)(ws + 209 * MB);             // 8 MB

    // weight preps
    prep_convw<<<(32 * 96 + 255) / 256, 256, 0, stream>>>(c1w, wc1, 32, 3, 8, 4);
    prep_convw<<<(64 * 288 + 255) / 256, 256, 0, stream>>>(c2w, wc2, 64, 32, 32, 3);
    prep_convw<<<(128 * 576 + 255) / 256, 256, 0, stream>>>(c3w, wc3, 128, 64, 64, 3);
    transpose_w_fc1<<<dim3(64, 32), 256, 0, stream>>>(f1w, wf1);
    transpose_w<<<dim3(32, 32), 256, 0, stream>>>(f2w, wf2, 1024, 1024);
    transpose_w<<<dim3(32, 32), 256, 0, stream>>>(f3w, wf3, 1024, 1024);
    transpose_w<<<dim3(32, 32), 256, 0, stream>>>(f4w, wf4, 1024, 1024);
    transpose_w<<<dim3(32, 8),  256, 0, stream>>>(f5w, wf5, 1024, 256);

    // shuffle + target
    rank_kernel<<<BATCH / 256, 256, 0, stream>>>(noise, ids, out + (size_t)BATCH * 256);
    shuffle_transpose<<<dim3(32, 64), 256, 0, stream>>>(x, ids, act0);

    // convs
    conv1_mfma<<<dim3(256, 1, 32), 256, 0, stream>>>(act0, wc1, c1b, act1);
    conv_gemm<32, 16, 64,  false, 4><<<dim3(64, 32), 256, 0, stream>>>(act1, wc2, c2b, act2);
    conv_gemm<64, 8,  128, true,  2><<<dim3(16, 32), 256, 0, stream>>>(act2, wc3, c3b, act3);

    // FC chain
    fc_mfma<true,  false><<<dim3(8, 32), 256, 0, stream>>>(act3, wf1, f1b, fcb1, BATCH, 1024, 2048);
    fc_mfma<true,  false><<<dim3(8, 32), 256, 0, stream>>>(fcb1, wf2, f2b, fcb2, BATCH, 1024, 1024);
    fc_mfma<true,  false><<<dim3(8, 32), 256, 0, stream>>>(fcb2, wf3, f3b, fcb1, BATCH, 1024, 1024);
    fc_mfma<true,  false><<<dim3(8, 32), 256, 0, stream>>>(fcb1, wf4, f4b, fcb2, BATCH, 1024, 1024);
    fc_mfma<false, true ><<<dim3(2, 32), 256, 0, stream>>>(fcb2, wf5, f5b, out, BATCH, 256, 1024);
}

// Round 9
// 330.956 us; speedup vs baseline: 1.5849x; 1.2517x over previous
//
#include <hip/hip_runtime.h>

#define BATCH 4096
#define NPATCH 16

typedef __attribute__((ext_vector_type(8)))  short  short8;
typedef __attribute__((ext_vector_type(4)))  float  f32x4;
typedef __attribute__((ext_vector_type(16))) float  f32x16;
typedef unsigned short ushort_t;

__device__ __forceinline__ ushort_t f2bf(float f) {
    union { float f; unsigned u; } x; x.f = f;
    unsigned r = x.u + 0x7FFFu + ((x.u >> 16) & 1u);
    return (ushort_t)(r >> 16);
}

__device__ __forceinline__ void gload_lds16(const void* g, void* l) {
    __builtin_amdgcn_global_load_lds((const __attribute__((address_space(1))) void*)g,
                                     (__attribute__((address_space(3))) void*)l, 16, 0, 0);
}

// ---------------------------------------------------------------------------
// rank: ids_shuffle (ws) + ids_restore -> target (f32, d_out tail)
// ---------------------------------------------------------------------------
__global__ void rank_kernel(const float* __restrict__ noise,
                            int* __restrict__ ids_shuffle,
                            float* __restrict__ target_out) {
    int n = blockIdx.x * 256 + threadIdx.x;
    if (n >= BATCH) return;
    float v[NPATCH];
#pragma unroll
    for (int i = 0; i < NPATCH; i++) v[i] = noise[n * NPATCH + i];
#pragma unroll
    for (int j = 0; j < NPATCH; j++) {
        int r = 0;
#pragma unroll
        for (int i = 0; i < NPATCH; i++)
            if (v[i] < v[j] || (v[i] == v[j] && i < j)) r++;
        ids_shuffle[n * NPATCH + r] = j;
        target_out[n * NPATCH + j] = (float)r;
    }
}

// ---------------------------------------------------------------------------
// patch-shuffle + transpose, f32 NCHW -> bf16 [32h][36wpad][4096n][8icpad]
// ---------------------------------------------------------------------------
__global__ void shuffle_transpose(const float* __restrict__ x,
                                  const int* __restrict__ ids,
                                  ushort_t* __restrict__ y) {
    __shared__ float tile[3][64][33];
    int h = blockIdx.x;
    int n0 = blockIdx.y << 6;
    int t = threadIdx.x;
    int w = t & 31;
    int jrow = (h >> 3) << 2;
#pragma unroll
    for (int r = 0; r < 8; r++) {
        int nl = (t >> 5) + (r << 3);
        int n = n0 + nl;
        int j = jrow + (w >> 3);
        int p = ids[(n << 4) + j];
        int sh = ((p >> 2) << 3) | (h & 7);
        int sw = ((p & 3) << 3) | (w & 7);
#pragma unroll
        for (int c = 0; c < 3; c++)
            tile[c][nl][w] = x[n * 3072 + (c << 10) + (sh << 5) + sw];
    }
    __syncthreads();
    int sub = t >> 6, nl = t & 63;
    int n = n0 + nl;
#pragma unroll
    for (int q = 0; q < 9; q++) {
        int wp = sub * 9 + q;            // 0..35
        int iw = wp - 1;
        ushort_t u[8];
#pragma unroll
        for (int e = 0; e < 8; e++) {
            float v = (e < 3 && iw >= 0 && iw < 32) ? tile[e][nl][iw] : 0.f;
            u[e] = f2bf(v);
        }
        *(uint4*)(y + ((size_t)(h * 36 + wp) * 4096 + n) * 8) = *(const uint4*)u;
    }
}

// ---------------------------------------------------------------------------
// conv weight prep: OIHW f32 -> [oc][k] bf16, k = kh*(KWP*ICP)+kw*ICP+ic
// ---------------------------------------------------------------------------
__global__ void prep_convw(const float* __restrict__ W, ushort_t* __restrict__ WT,
                           int OC, int IC, int ICP, int KWP) {
    int KP = 3 * KWP * ICP;
    int i = blockIdx.x * 256 + threadIdx.x;
    if (i >= OC * KP) return;
    int oc = i / KP, k = i % KP;
    int kh = k / (KWP * ICP);
    int kw = (k / ICP) % KWP;
    int ic = k % ICP;
    ushort_t v = 0;
    if (kw < 3 && ic < IC)
        v = f2bf(W[((oc * IC + ic) * 3 + kh) * 3 + kw]);
    WT[i] = v;
}

// ---------------------------------------------------------------------------
// FC weight prep: [K][N] f32 -> [N][K] bf16
// ---------------------------------------------------------------------------
__global__ void transpose_w(const float* __restrict__ W, ushort_t* __restrict__ WT,
                            int K, int N) {
    __shared__ ushort_t t[32][33];
    int kb = blockIdx.x * 32, nb = blockIdx.y * 32;
    int tx = threadIdx.x & 31, ty = threadIdx.x >> 5;
#pragma unroll
    for (int i = 0; i < 32; i += 8)
        t[ty + i][tx] = f2bf(W[(size_t)(kb + ty + i) * N + nb + tx]);
    __syncthreads();
#pragma unroll
    for (int i = 0; i < 32; i += 8)
        WT[(size_t)(nb + ty + i) * K + kb + tx] = t[tx][ty + i];
}

// fc1 weights with permuted k: WT[n][k'] = W[k][n], k' = hw*128+c, k = c*16+hw
__global__ void transpose_w_fc1(const float* __restrict__ W, ushort_t* __restrict__ WT) {
    __shared__ ushort_t t[32][33];
    int kb = blockIdx.x * 32, nb = blockIdx.y * 32;
    int hw = kb >> 7, c0 = kb & 127;
    int tx = threadIdx.x & 31, ty = threadIdx.x >> 5;
#pragma unroll
    for (int i = 0; i < 32; i += 8)
        t[ty + i][tx] = f2bf(W[(size_t)((c0 + ty + i) * 16 + hw) * 1024 + nb + tx]);
    __syncthreads();
#pragma unroll
    for (int i = 0; i < 32; i += 8)
        WT[(size_t)(nb + ty + i) * 2048 + kb + tx] = t[tx][ty + i];
}

// ---------------------------------------------------------------------------
// conv1: 3->32, 3x3 SAME + relu + pool, mfma 32x32x16 bf16.
// X: [32][36][4096][8] bf16 (padded). WT: [32oc][96] (k = kh*32+kw*8+ic).
// ---------------------------------------------------------------------------
__global__ __launch_bounds__(256, 4)
void conv1_mfma(const ushort_t* __restrict__ X, const ushort_t* __restrict__ WT,
                const float* __restrict__ bias, ushort_t* __restrict__ Y) {
    const int tid = threadIdx.x;
    const int wid = tid >> 6, lane = tid & 63;
    const int nl = lane & 31, kc = lane >> 5;
    const int pos = blockIdx.x;
    const int ph = pos >> 4, pw = pos & 15;
    const int n = (blockIdx.z * 4 + wid) * 32 + nl;

    f32x16 acc[4];
#pragma unroll
    for (int p = 0; p < 4; ++p)
#pragma unroll
        for (int r = 0; r < 16; ++r) acc[p][r] = 0.f;

    const ushort_t* wp_ = WT + nl * 96 + kc * 8;
#pragma unroll
    for (int s = 0; s < 6; ++s) {
        int kh = s >> 1;
        int kw = ((s & 1) << 1) + kc;
        short8 af = *(const short8*)(wp_ + s * 16);
        short8 bf[4];
#pragma unroll
        for (int p = 0; p < 4; ++p) {
            int pr = p >> 1, pc = p & 1;
            int ih = 2 * ph + pr - 1 + kh;
            int wpad = 2 * pw + pc + kw;
            short8 b = {};
            if ((unsigned)ih < 32u)
                b = *(const short8*)(X + ((size_t)(ih * 36 + wpad) * 4096 + n) * 8);
            bf[p] = b;
        }
#pragma unroll
        for (int p = 0; p < 4; ++p)
            acc[p] = __builtin_amdgcn_mfma_f32_32x32x16_bf16(af, bf[p], acc[p], 0, 0, 0);
    }
#pragma unroll
    for (int g = 0; g < 4; ++g) {
        ushort_t u[4];
        int ocb = 8 * g + 4 * kc;
#pragma unroll
        for (int j = 0; j < 4; ++j) {
            int reg = 4 * g + j;
            float mx = fmaxf(fmaxf(acc[0][reg], acc[1][reg]), fmaxf(acc[2][reg], acc[3][reg]));
            u[j] = f2bf(fmaxf(mx + bias[ocb + j], 0.f));
        }
        *(uint2*)(Y + ((size_t)(ph * 16 + pw) * 4096 + n) * 32 + ocb) = *(const uint2*)u;
    }
}

// ---------------------------------------------------------------------------
// conv2: 32->64 + relu + pool as window-staged GEMM.
// Block = 1 pooled pos x 64 n x all 64 oc. Weights [64][288] resident in LDS
// (36 KB, staged once -> L2-served for all blocks). The 4x4 unique input
// window = 16 slabs [64n][32ic] (4 KB), double-buffered, one barrier/slab.
// XCD-chunked swizzle: consecutive pos-blocks of one n-tile share an XCD L2.
// ---------------------------------------------------------------------------
__global__ __launch_bounds__(256, 2)
void conv2_gemm(const ushort_t* __restrict__ X, const ushort_t* __restrict__ WT,
                const float* __restrict__ bias, ushort_t* __restrict__ Y) {
    __shared__ ushort_t As[64 * 288];      // 36 KB, resident
    __shared__ ushort_t Bs[2][64 * 32];    // 2 x 4 KB dbuf
    const int tid = threadIdx.x;
    const int wid = tid >> 6;
    const int lane = tid & 63;
    const int l15 = lane & 15, l4 = lane >> 4;
    const int wm = wid >> 1, wn = wid & 1;       // 2x2 waves: oc x n halves
    // bijective XCD-chunk swizzle (4096 blocks, 8 XCDs)
    const int orig = blockIdx.x;
    const int lin = (orig & 7) * 512 + (orig >> 3);
    const int pos = lin & 63;                    // pos fast -> window reuse in L2
    const int n0 = (lin >> 6) * 64;
    const int ph = pos >> 3, pw = pos & 7;

    f32x4 acc[4][2][2];
#pragma unroll
    for (int p = 0; p < 4; ++p)
#pragma unroll
        for (int i = 0; i < 2; ++i)
#pragma unroll
            for (int j = 0; j < 2; ++j)
#pragma unroll
                for (int r = 0; r < 4; ++r) acc[p][i][j][r] = 0.f;

    // prologue: stage all weights (64 rows x 36 chunks = 9 passes)
#pragma unroll
    for (int pass = 0; pass < 9; ++pass) {
        int idx = pass * 256 + tid;
        int m = idx / 36, ss = idx % 36;
        int cc = ss ^ ((m >> 1) & 3);
        gload_lds16(WT + (size_t)m * 288 + cc * 8, &As[(pass * 256 + wid * 64) * 8]);
    }
    // stage slab 0 (dh=0, dw=0) if in bounds
    {
        int ih = 2 * ph - 1, iw = 2 * pw - 1;
        if (ih >= 0 && iw >= 0) {
            int m = tid >> 2, ss = tid & 3;
            int cc = ss ^ ((m >> 1) & 3);
            gload_lds16(X + ((size_t)(ih * 16 + iw) * 4096 + n0 + m) * 32 + cc * 8,
                        &Bs[0][wid * 64 * 8]);
        }
    }
    __syncthreads();

    for (int s = 0; s < 16; ++s) {
        // stage next slab into the other buffer
        int nb = s + 1;
        if (nb < 16) {
            int ih = 2 * ph - 1 + (nb >> 2), iw = 2 * pw - 1 + (nb & 3);
            if ((unsigned)ih < 16u && (unsigned)iw < 16u) {
                int m = tid >> 2, ss = tid & 3;
                int cc = ss ^ ((m >> 1) & 3);
                gload_lds16(X + ((size_t)(ih * 16 + iw) * 4096 + n0 + m) * 32 + cc * 8,
                            &Bs[nb & 1][wid * 64 * 8]);
            }
        }
        // compute current slab
        int dh = s >> 2, dw = s & 3;
        int ih = 2 * ph - 1 + dh, iw = 2 * pw - 1 + dw;
        if ((unsigned)ih < 16u && (unsigned)iw < 16u) {
            short8 bf[2];
#pragma unroll
            for (int j = 0; j < 2; ++j) {
                int m = wn * 32 + j * 16 + l15;
                bf[j] = *(const short8*)(&Bs[s & 1][m * 32 + ((l4 ^ ((m >> 1) & 3)) * 8)]);
            }
#pragma unroll
            for (int p = 0; p < 4; ++p) {
                int pr = p >> 1, pc = p & 1;
                int kh = dh - pr, kw = dw - pc;
                if (kh >= 0 && kh < 3 && kw >= 0 && kw < 3) {
                    int tap = kh * 3 + kw;
                    short8 af[2];
#pragma unroll
                    for (int i = 0; i < 2; ++i) {
                        int m = wm * 32 + i * 16 + l15;
                        int g = tap * 4 + l4;
                        af[i] = *(const short8*)(&As[m * 288 + ((g ^ ((m >> 1) & 3)) * 8)]);
                    }
#pragma unroll
                    for (int i = 0; i < 2; ++i)
#pragma unroll
                        for (int j = 0; j < 2; ++j)
                            acc[p][i][j] = __builtin_amdgcn_mfma_f32_16x16x32_bf16(
                                af[i], bf[j], acc[p][i][j], 0, 0, 0);
                }
            }
        }
        __syncthreads();
    }

    // pool-max over 4 positions + bias + relu; write [pos][4096n][64oc]
#pragma unroll
    for (int i = 0; i < 2; ++i) {
        int oc_l = wm * 32 + i * 16 + l4 * 4;
#pragma unroll
        for (int j = 0; j < 2; ++j) {
            int n = n0 + wn * 32 + j * 16 + l15;
            ushort_t u[4];
#pragma unroll
            for (int r = 0; r < 4; ++r) {
                float mx = fmaxf(fmaxf(acc[0][i][j][r], acc[1][i][j][r]),
                                 fmaxf(acc[2][i][j][r], acc[3][i][j][r]));
                u[r] = f2bf(fmaxf(mx + bias[oc_l + r], 0.f));
            }
            *(uint2*)(Y + ((size_t)pos * 4096 + n) * 64 + oc_l) = *(const uint2*)u;
        }
    }
}

// ---------------------------------------------------------------------------
// conv3 as LDS-staged GEMM + pool-max (round-8 structure + XCD swizzle).
// Block = one pooled pos x 128 n x all 128 oc; per tap stage A/B, mfma.
// ---------------------------------------------------------------------------
template <int IC, int H, int OC, bool FC_EPI, int MINB>
__global__ __launch_bounds__(256, MINB)
void conv_gemm(const ushort_t* __restrict__ X, const ushort_t* __restrict__ WT,
               const float* __restrict__ bias, ushort_t* __restrict__ Y) {
    constexpr int PW = H / 2;
    constexpr int K  = 9 * IC;
    constexpr int CH = IC / 8;
    constexpr int CM = CH - 1;
    constexpr int KK = IC / 32;
    constexpr int WM = (OC == 128) ? 2 : 1;
    constexpr int WN = 4 / WM;
    constexpr int WTM = OC / WM / 16;
    constexpr int WTN = 128 / WN / 16;
    constexpr int APASS = OC * CH / 256;
    constexpr int BPASS = 128 * CH / 256;
    constexpr int NPOS = PW * PW;

    __shared__ ushort_t As[OC * IC];
    __shared__ ushort_t Bs[128 * IC];
    const int tid = threadIdx.x;
    const int wid = tid >> 6, lane = tid & 63;
    const int wm = wid / WN, wn = wid % WN;
    const int l15 = lane & 15, l4 = lane >> 4;
    // bijective XCD swizzle over NPOS * 32 blocks
    const int orig = blockIdx.x;
    const int nwg = NPOS * 32;
    const int lin = (orig & 7) * (nwg / 8) + (orig >> 3);
    const int ph = (lin % NPOS) / PW, pw = (lin % NPOS) % PW;
    const int n0 = (lin / NPOS) * 128;

    f32x4 acc[WTM][WTN], mx[WTM][WTN];

    for (int p = 0; p < 4; ++p) {
#pragma unroll
        for (int i = 0; i < WTM; ++i)
#pragma unroll
            for (int j = 0; j < WTN; ++j)
#pragma unroll
                for (int r = 0; r < 4; ++r) acc[i][j][r] = 0.f;
        const int pr = p >> 1, pc = p & 1;
        for (int t = 0; t < 9; ++t) {
            const int kh = t / 3, kw = t % 3;
            const int ih = 2 * ph + pr - 1 + kh;
            const int iw = 2 * pw + pc - 1 + kw;
            if ((unsigned)ih >= (unsigned)H || (unsigned)iw >= (unsigned)H) continue;
            __syncthreads();
            const ushort_t* bsrc = X + (size_t)(ih * H + iw) * 4096 * IC + (size_t)n0 * IC;
#pragma unroll
            for (int pass = 0; pass < APASS; ++pass) {
                int idx = pass * 256 + tid;
                int m = idx / CH, ss = idx % CH;
                int cc = ss ^ (m & CM);
                gload_lds16(WT + (size_t)m * K + t * IC + cc * 8,
                            &As[(pass * 256 + wid * 64) * 8]);
            }
#pragma unroll
            for (int pass = 0; pass < BPASS; ++pass) {
                int idx = pass * 256 + tid;
                int m = idx / CH, ss = idx % CH;
                int cc = ss ^ (m & CM);
                gload_lds16(bsrc + (size_t)m * IC + cc * 8,
                            &Bs[(pass * 256 + wid * 64) * 8]);
            }
            __syncthreads();
#pragma unroll
            for (int kk = 0; kk < KK; ++kk) {
                short8 af[WTM], bf[WTN];
                int c = kk * 4 + l4;
#pragma unroll
                for (int i = 0; i < WTM; ++i) {
                    int m = wm * (WTM * 16) + i * 16 + l15;
                    af[i] = *(const short8*)(As + m * IC + ((c ^ (m & CM)) * 8));
                }
#pragma unroll
                for (int j = 0; j < WTN; ++j) {
                    int m = wn * (WTN * 16) + j * 16 + l15;
                    bf[j] = *(const short8*)(Bs + m * IC + ((c ^ (m & CM)) * 8));
                }
#pragma unroll
                for (int i = 0; i < WTM; ++i)
#pragma unroll
                    for (int j = 0; j < WTN; ++j)
                        acc[i][j] = __builtin_amdgcn_mfma_f32_16x16x32_bf16(
                            af[i], bf[j], acc[i][j], 0, 0, 0);
            }
        }
#pragma unroll
        for (int i = 0; i < WTM; ++i)
#pragma unroll
            for (int j = 0; j < WTN; ++j)
#pragma unroll
                for (int r = 0; r < 4; ++r)
                    mx[i][j][r] = (p == 0) ? acc[i][j][r]
                                           : fmaxf(mx[i][j][r], acc[i][j][r]);
    }

#pragma unroll
    for (int i = 0; i < WTM; ++i) {
        int oc_l = wm * (WTM * 16) + i * 16 + l4 * 4;
#pragma unroll
        for (int j = 0; j < WTN; ++j) {
            int n = n0 + wn * (WTN * 16) + j * 16 + l15;
            ushort_t u[4];
#pragma unroll
            for (int r = 0; r < 4; ++r)
                u[r] = f2bf(fmaxf(mx[i][j][r] + bias[oc_l + r], 0.f));
            if (FC_EPI)
                *(uint2*)(Y + (size_t)n * 2048 + (ph * 4 + pw) * 128 + oc_l) = *(const uint2*)u;
            else
                *(uint2*)(Y + ((size_t)(ph * PW + pw) * 4096 + n) * OC + oc_l) = *(const uint2*)u;
        }
    }
}

// ---------------------------------------------------------------------------
// FC GEMM: C[M][N] = act(A[M][K] @ W + b), BT[N][K]. 128x128 tile, BK=64,
// 4 waves, mfma 16x16x32, global_load_lds + stage_rc XOR swizzle.
// ---------------------------------------------------------------------------
template <bool RELU, bool F32OUT>
__global__ __launch_bounds__(256, 2)
void fc_mfma(const ushort_t* __restrict__ A, const ushort_t* __restrict__ BT,
             const float* __restrict__ bias, void* __restrict__ Cout,
             int M, int N, int K) {
    __shared__ ushort_t As[128 * 64];
    __shared__ ushort_t Bs[128 * 64];
    const int tid = threadIdx.x;
    const int wid = tid >> 6, lane = tid & 63;
    const int wr = wid >> 1, wc = wid & 1;
    const int tm = blockIdx.y * 128, tn = blockIdx.x * 128;
    const int l15 = lane & 15, l4 = lane >> 4;

    f32x4 acc[4][4];
#pragma unroll
    for (int i = 0; i < 4; ++i)
#pragma unroll
        for (int j = 0; j < 4; ++j)
#pragma unroll
            for (int r = 0; r < 4; ++r) acc[i][j][r] = 0.f;

    for (int k0 = 0; k0 < K; k0 += 64) {
        __syncthreads();
#pragma unroll
        for (int pass = 0; pass < 4; ++pass) {
            int idx = pass * 256 + tid;
            int m = idx >> 3, ss = idx & 7;
            int cc = ss ^ (m & 7);
            gload_lds16(A  + (size_t)(tm + m) * K + k0 + cc * 8,
                        &As[(pass * 256 + wid * 64) * 8]);
            gload_lds16(BT + (size_t)(tn + m) * K + k0 + cc * 8,
                        &Bs[(pass * 256 + wid * 64) * 8]);
        }
        __syncthreads();
#pragma unroll
        for (int kk = 0; kk < 2; ++kk) {
            short8 af[4], bfr[4];
            int c = kk * 4 + l4;
#pragma unroll
            for (int i = 0; i < 4; ++i) {
                int m = wr * 64 + i * 16 + l15;
                af[i]  = *(const short8*)(As + m * 64 + (c ^ (m & 7)) * 8);
                int nn = wc * 64 + i * 16 + l15;
                bfr[i] = *(const short8*)(Bs + nn * 64 + (c ^ (nn & 7)) * 8);
            }
#pragma unroll
            for (int i = 0; i < 4; ++i)
#pragma unroll
                for (int j = 0; j < 4; ++j)
                    acc[i][j] = __builtin_amdgcn_mfma_f32_16x16x32_bf16(
                        af[i], bfr[j], acc[i][j], 0, 0, 0);
        }
    }
#pragma unroll
    for (int i = 0; i < 4; ++i) {
        int row = tm + wr * 64 + i * 16 + l4 * 4;
#pragma unroll
        for (int j = 0; j < 4; ++j) {
            int col = tn + wc * 64 + j * 16 + l15;
            float bv = bias[col];
#pragma unroll
            for (int r = 0; r < 4; ++r) {
                float v = acc[i][j][r] + bv;
                if (RELU) v = fmaxf(v, 0.f);
                if (F32OUT)
                    ((float*)Cout)[(size_t)(row + r) * N + col] = v;
                else
                    ((ushort_t*)Cout)[(size_t)(row + r) * N + col] = f2bf(v);
            }
        }
    }
}

// ---------------------------------------------------------------------------
extern "C" void kernel_launch(void* const* d_in, const int* in_sizes, int n_in,
                              void* d_out, int out_size, void* d_ws, size_t ws_size,
                              hipStream_t stream) {
    const float* x     = (const float*)d_in[0];
    const float* noise = (const float*)d_in[1];
    const float* c1w = (const float*)d_in[2];  const float* c1b = (const float*)d_in[3];
    const float* c2w = (const float*)d_in[4];  const float* c2b = (const float*)d_in[5];
    const float* c3w = (const float*)d_in[6];  const float* c3b = (const float*)d_in[7];
    const float* f1w = (const float*)d_in[8];  const float* f1b = (const float*)d_in[9];
    const float* f2w = (const float*)d_in[10]; const float* f2b = (const float*)d_in[11];
    const float* f3w = (const float*)d_in[12]; const float* f3b = (const float*)d_in[13];
    const float* f4w = (const float*)d_in[14]; const float* f4b = (const float*)d_in[15];
    const float* f5w = (const float*)d_in[16]; const float* f5b = (const float*)d_in[17];
    float* out = (float*)d_out;

    char* ws = (char*)d_ws;
    const size_t MB = 1ull << 20;
    int*      ids  = (int*)ws;                               // 256 KB
    ushort_t* wc1  = (ushort_t*)(ws + 1 * MB);               // 6 KB
    ushort_t* wc2  = (ushort_t*)(ws + 1 * MB + 64 * 1024);   // 36 KB
    ushort_t* wc3  = (ushort_t*)(ws + 1 * MB + 128 * 1024);  // 144 KB
    ushort_t* wf1  = (ushort_t*)(ws + 2 * MB);               // 4 MB
    ushort_t* wf2  = (ushort_t*)(ws + 6 * MB);               // 2 MB
    ushort_t* wf3  = (ushort_t*)(ws + 8 * MB);               // 2 MB
    ushort_t* wf4  = (ushort_t*)(ws + 10 * MB);              // 2 MB
    ushort_t* wf5  = (ushort_t*)(ws + 12 * MB);              // 0.5 MB
    ushort_t* act0 = (ushort_t*)(ws + 13 * MB);              // 75.5 MB [32][36][4096][8]
    ushort_t* act1 = (ushort_t*)(ws + 89 * MB);              // 64 MB  [16][16][4096][32]
    ushort_t* act2 = (ushort_t*)(ws + 153 * MB);             // 32 MB  [8][8][4096][64]
    ushort_t* act3 = (ushort_t*)(ws + 185 * MB);             // 16 MB  [4096][2048]
    ushort_t* fcb1 = (ushort_t*)(ws + 201 * MB);             // 8 MB
    ushort_t* fcb2 = (ushort_t*)(ws + 209 * MB);             // 8 MB

    // weight preps
    prep_convw<<<(32 * 96 + 255) / 256, 256, 0, stream>>>(c1w, wc1, 32, 3, 8, 4);
    prep_convw<<<(64 * 288 + 255) / 256, 256, 0, stream>>>(c2w, wc2, 64, 32, 32, 3);
    prep_convw<<<(128 * 576 + 255) / 256, 256, 0, stream>>>(c3w, wc3, 128, 64, 64, 3);
    transpose_w_fc1<<<dim3(64, 32), 256, 0, stream>>>(f1w, wf1);
    transpose_w<<<dim3(32, 32), 256, 0, stream>>>(f2w, wf2, 1024, 1024);
    transpose_w<<<dim3(32, 32), 256, 0, stream>>>(f3w, wf3, 1024, 1024);
    transpose_w<<<dim3(32, 32), 256, 0, stream>>>(f4w, wf4, 1024, 1024);
    transpose_w<<<dim3(32, 8),  256, 0, stream>>>(f5w, wf5, 1024, 256);

    // shuffle + target
    rank_kernel<<<BATCH / 256, 256, 0, stream>>>(noise, ids, out + (size_t)BATCH * 256);
    shuffle_transpose<<<dim3(32, 64), 256, 0, stream>>>(x, ids, act0);

    // convs
    conv1_mfma<<<dim3(256, 1, 32), 256, 0, stream>>>(act0, wc1, c1b, act1);
    conv2_gemm<<<dim3(4096), 256, 0, stream>>>(act1, wc2, c2b, act2);
    conv_gemm<64, 8, 128, true, 2><<<dim3(512), 256, 0, stream>>>(act2, wc3, c3b, act3);

    // FC chain
    fc_mfma<true,  false><<<dim3(8, 32), 256, 0, stream>>>(act3, wf1, f1b, fcb1, BATCH, 1024, 2048);
    fc_mfma<true,  false><<<dim3(8, 32), 256, 0, stream>>>(fcb1, wf2, f2b, fcb2, BATCH, 1024, 1024);
    fc_mfma<true,  false><<<dim3(8, 32), 256, 0, stream>>>(fcb2, wf3, f3b, fcb1, BATCH, 1024, 1024);
    fc_mfma<true,  false><<<dim3(8, 32), 256, 0, stream>>>(fcb1, wf4, f4b, fcb2, BATCH, 1024, 1024);
    fc_mfma<false, true ><<<dim3(2, 32), 256, 0, stream>>>(fcb2, wf5, f5b, out, BATCH, 256, 1024);
}

// Round 10
// 318.878 us; speedup vs baseline: 1.6449x; 1.0379x over previous
//
#include <hip/hip_runtime.h>

#define BATCH 4096
#define NPATCH 16

typedef __attribute__((ext_vector_type(8)))  short  short8;
typedef __attribute__((ext_vector_type(4)))  float  f32x4;
typedef __attribute__((ext_vector_type(16))) float  f32x16;
typedef unsigned short ushort_t;

__device__ __forceinline__ ushort_t f2bf(float f) {
    union { float f; unsigned u; } x; x.f = f;
    unsigned r = x.u + 0x7FFFu + ((x.u >> 16) & 1u);
    return (ushort_t)(r >> 16);
}

__device__ __forceinline__ void gload_lds16(const void* g, void* l) {
    __builtin_amdgcn_global_load_lds((const __attribute__((address_space(1))) void*)g,
                                     (__attribute__((address_space(3))) void*)l, 16, 0, 0);
}

// ---------------------------------------------------------------------------
// rank: ids_shuffle (ws) + ids_restore -> target (f32, d_out tail)
// ---------------------------------------------------------------------------
__global__ void rank_kernel(const float* __restrict__ noise,
                            int* __restrict__ ids_shuffle,
                            float* __restrict__ target_out) {
    int n = blockIdx.x * 256 + threadIdx.x;
    if (n >= BATCH) return;
    float v[NPATCH];
#pragma unroll
    for (int i = 0; i < NPATCH; i++) v[i] = noise[n * NPATCH + i];
#pragma unroll
    for (int j = 0; j < NPATCH; j++) {
        int r = 0;
#pragma unroll
        for (int i = 0; i < NPATCH; i++)
            if (v[i] < v[j] || (v[i] == v[j] && i < j)) r++;
        ids_shuffle[n * NPATCH + r] = j;
        target_out[n * NPATCH + j] = (float)r;
    }
}

// ---------------------------------------------------------------------------
// patch-shuffle + transpose, f32 NCHW -> bf16 [32h][36wpad][4096n][8icpad]
// ---------------------------------------------------------------------------
__global__ void shuffle_transpose(const float* __restrict__ x,
                                  const int* __restrict__ ids,
                                  ushort_t* __restrict__ y) {
    __shared__ float tile[3][64][33];
    int h = blockIdx.x;
    int n0 = blockIdx.y << 6;
    int t = threadIdx.x;
    int w = t & 31;
    int jrow = (h >> 3) << 2;
#pragma unroll
    for (int r = 0; r < 8; r++) {
        int nl = (t >> 5) + (r << 3);
        int n = n0 + nl;
        int j = jrow + (w >> 3);
        int p = ids[(n << 4) + j];
        int sh = ((p >> 2) << 3) | (h & 7);
        int sw = ((p & 3) << 3) | (w & 7);
#pragma unroll
        for (int c = 0; c < 3; c++)
            tile[c][nl][w] = x[n * 3072 + (c << 10) + (sh << 5) + sw];
    }
    __syncthreads();
    int sub = t >> 6, nl = t & 63;
    int n = n0 + nl;
#pragma unroll
    for (int q = 0; q < 9; q++) {
        int wp = sub * 9 + q;            // 0..35
        int iw = wp - 1;
        ushort_t u[8];
#pragma unroll
        for (int e = 0; e < 8; e++) {
            float v = (e < 3 && iw >= 0 && iw < 32) ? tile[e][nl][iw] : 0.f;
            u[e] = f2bf(v);
        }
        *(uint4*)(y + ((size_t)(h * 36 + wp) * 4096 + n) * 8) = *(const uint4*)u;
    }
}

// ---------------------------------------------------------------------------
// conv weight prep: OIHW f32 -> [oc][k] bf16, k = kh*(KWP*ICP)+kw*ICP+ic
// ---------------------------------------------------------------------------
__global__ void prep_convw(const float* __restrict__ W, ushort_t* __restrict__ WT,
                           int OC, int IC, int ICP, int KWP) {
    int KP = 3 * KWP * ICP;
    int i = blockIdx.x * 256 + threadIdx.x;
    if (i >= OC * KP) return;
    int oc = i / KP, k = i % KP;
    int kh = k / (KWP * ICP);
    int kw = (k / ICP) % KWP;
    int ic = k % ICP;
    ushort_t v = 0;
    if (kw < 3 && ic < IC)
        v = f2bf(W[((oc * IC + ic) * 3 + kh) * 3 + kw]);
    WT[i] = v;
}

// ---------------------------------------------------------------------------
// FC weight prep: [K][N] f32 -> [N][K] bf16
// ---------------------------------------------------------------------------
__global__ void transpose_w(const float* __restrict__ W, ushort_t* __restrict__ WT,
                            int K, int N) {
    __shared__ ushort_t t[32][33];
    int kb = blockIdx.x * 32, nb = blockIdx.y * 32;
    int tx = threadIdx.x & 31, ty = threadIdx.x >> 5;
#pragma unroll
    for (int i = 0; i < 32; i += 8)
        t[ty + i][tx] = f2bf(W[(size_t)(kb + ty + i) * N + nb + tx]);
    __syncthreads();
#pragma unroll
    for (int i = 0; i < 32; i += 8)
        WT[(size_t)(nb + ty + i) * K + kb + tx] = t[tx][ty + i];
}

// fc1 weights with permuted k: WT[n][k'] = W[k][n], k' = hw*128+c, k = c*16+hw
__global__ void transpose_w_fc1(const float* __restrict__ W, ushort_t* __restrict__ WT) {
    __shared__ ushort_t t[32][33];
    int kb = blockIdx.x * 32, nb = blockIdx.y * 32;
    int hw = kb >> 7, c0 = kb & 127;
    int tx = threadIdx.x & 31, ty = threadIdx.x >> 5;
#pragma unroll
    for (int i = 0; i < 32; i += 8)
        t[ty + i][tx] = f2bf(W[(size_t)((c0 + ty + i) * 16 + hw) * 1024 + nb + tx]);
    __syncthreads();
#pragma unroll
    for (int i = 0; i < 32; i += 8)
        WT[(size_t)(nb + ty + i) * 2048 + kb + tx] = t[tx][ty + i];
}

// ---------------------------------------------------------------------------
// conv1 v2: 3->32 + relu + pool via mfma 16x16x32.
// X: [32][36][4096][8] bf16. WT: [32oc][96] (k = kh*32 + kw*8 + ic).
// Wave = 16 n x 32 oc x 4 conv positions; acc = 32 regs; B shared across
// (pr,kh) row coincidences (8 loads/wave). A-frags in regs.
// ---------------------------------------------------------------------------
__global__ __launch_bounds__(256, 4)
void conv1_mfma(const ushort_t* __restrict__ X, const ushort_t* __restrict__ WT,
                const float* __restrict__ bias, ushort_t* __restrict__ Y) {
    const int tid = threadIdx.x;
    const int wid = tid >> 6, lane = tid & 63;
    const int l15 = lane & 15, l4 = lane >> 4;
    const int pos = blockIdx.x;
    const int ph = pos >> 4, pw = pos & 15;
    const int n = (blockIdx.y << 6) + (wid << 4) + l15;

    short8 af[3][2];
#pragma unroll
    for (int kh = 0; kh < 3; ++kh)
#pragma unroll
        for (int i = 0; i < 2; ++i)
            af[kh][i] = *(const short8*)(WT + (i * 16 + l15) * 96 + kh * 32 + l4 * 8);

    f32x4 acc[2][4];
#pragma unroll
    for (int i = 0; i < 2; ++i)
#pragma unroll
        for (int p = 0; p < 4; ++p)
#pragma unroll
            for (int r = 0; r < 4; ++r) acc[i][p][r] = 0.f;

#pragma unroll
    for (int pc = 0; pc < 2; ++pc)
#pragma unroll
        for (int rr = 0; rr < 4; ++rr) {
            int ih = 2 * ph - 1 + rr;
            if ((unsigned)ih >= 32u) continue;
            short8 bf = *(const short8*)(
                X + ((size_t)(ih * 36 + 2 * pw + pc + l4) * 4096 + n) * 8);
#pragma unroll
            for (int pr = 0; pr < 2; ++pr) {
                int kh = rr - pr;
                if (kh < 0 || kh > 2) continue;
#pragma unroll
                for (int i = 0; i < 2; ++i)
                    acc[i][pr * 2 + pc] = __builtin_amdgcn_mfma_f32_16x16x32_bf16(
                        af[kh][i], bf, acc[i][pr * 2 + pc], 0, 0, 0);
            }
        }

#pragma unroll
    for (int i = 0; i < 2; ++i) {
        int ocb = i * 16 + l4 * 4;
        ushort_t u[4];
#pragma unroll
        for (int r = 0; r < 4; ++r) {
            float mx = fmaxf(fmaxf(acc[i][0][r], acc[i][1][r]),
                             fmaxf(acc[i][2][r], acc[i][3][r]));
            u[r] = f2bf(fmaxf(mx + bias[ocb + r], 0.f));
        }
        *(uint2*)(Y + ((size_t)pos * 4096 + n) * 32 + ocb) = *(const uint2*)u;
    }
}

// ---------------------------------------------------------------------------
// conv2: 32->64 + relu + pool as window-staged GEMM (round-9, unchanged).
// ---------------------------------------------------------------------------
__global__ __launch_bounds__(256, 2)
void conv2_gemm(const ushort_t* __restrict__ X, const ushort_t* __restrict__ WT,
                const float* __restrict__ bias, ushort_t* __restrict__ Y) {
    __shared__ ushort_t As[64 * 288];      // 36 KB, resident
    __shared__ ushort_t Bs[2][64 * 32];    // 2 x 4 KB dbuf
    const int tid = threadIdx.x;
    const int wid = tid >> 6;
    const int lane = tid & 63;
    const int l15 = lane & 15, l4 = lane >> 4;
    const int wm = wid >> 1, wn = wid & 1;
    const int orig = blockIdx.x;
    const int lin = (orig & 7) * 512 + (orig >> 3);
    const int pos = lin & 63;
    const int n0 = (lin >> 6) * 64;
    const int ph = pos >> 3, pw = pos & 7;

    f32x4 acc[4][2][2];
#pragma unroll
    for (int p = 0; p < 4; ++p)
#pragma unroll
        for (int i = 0; i < 2; ++i)
#pragma unroll
            for (int j = 0; j < 2; ++j)
#pragma unroll
                for (int r = 0; r < 4; ++r) acc[p][i][j][r] = 0.f;

#pragma unroll
    for (int pass = 0; pass < 9; ++pass) {
        int idx = pass * 256 + tid;
        int m = idx / 36, ss = idx % 36;
        int cc = ss ^ ((m >> 1) & 3);
        gload_lds16(WT + (size_t)m * 288 + cc * 8, &As[(pass * 256 + wid * 64) * 8]);
    }
    {
        int ih = 2 * ph - 1, iw = 2 * pw - 1;
        if (ih >= 0 && iw >= 0) {
            int m = tid >> 2, ss = tid & 3;
            int cc = ss ^ ((m >> 1) & 3);
            gload_lds16(X + ((size_t)(ih * 16 + iw) * 4096 + n0 + m) * 32 + cc * 8,
                        &Bs[0][wid * 64 * 8]);
        }
    }
    __syncthreads();

    for (int s = 0; s < 16; ++s) {
        int nb = s + 1;
        if (nb < 16) {
            int ih = 2 * ph - 1 + (nb >> 2), iw = 2 * pw - 1 + (nb & 3);
            if ((unsigned)ih < 16u && (unsigned)iw < 16u) {
                int m = tid >> 2, ss = tid & 3;
                int cc = ss ^ ((m >> 1) & 3);
                gload_lds16(X + ((size_t)(ih * 16 + iw) * 4096 + n0 + m) * 32 + cc * 8,
                            &Bs[nb & 1][wid * 64 * 8]);
            }
        }
        int dh = s >> 2, dw = s & 3;
        int ih = 2 * ph - 1 + dh, iw = 2 * pw - 1 + dw;
        if ((unsigned)ih < 16u && (unsigned)iw < 16u) {
            short8 bf[2];
#pragma unroll
            for (int j = 0; j < 2; ++j) {
                int m = wn * 32 + j * 16 + l15;
                bf[j] = *(const short8*)(&Bs[s & 1][m * 32 + ((l4 ^ ((m >> 1) & 3)) * 8)]);
            }
#pragma unroll
            for (int p = 0; p < 4; ++p) {
                int pr = p >> 1, pc = p & 1;
                int kh = dh - pr, kw = dw - pc;
                if (kh >= 0 && kh < 3 && kw >= 0 && kw < 3) {
                    int tap = kh * 3 + kw;
                    short8 af[2];
#pragma unroll
                    for (int i = 0; i < 2; ++i) {
                        int m = wm * 32 + i * 16 + l15;
                        int g = tap * 4 + l4;
                        af[i] = *(const short8*)(&As[m * 288 + ((g ^ ((m >> 1) & 3)) * 8)]);
                    }
#pragma unroll
                    for (int i = 0; i < 2; ++i)
#pragma unroll
                        for (int j = 0; j < 2; ++j)
                            acc[p][i][j] = __builtin_amdgcn_mfma_f32_16x16x32_bf16(
                                af[i], bf[j], acc[p][i][j], 0, 0, 0);
                }
            }
        }
        __syncthreads();
    }

#pragma unroll
    for (int i = 0; i < 2; ++i) {
        int oc_l = wm * 32 + i * 16 + l4 * 4;
#pragma unroll
        for (int j = 0; j < 2; ++j) {
            int n = n0 + wn * 32 + j * 16 + l15;
            ushort_t u[4];
#pragma unroll
            for (int r = 0; r < 4; ++r) {
                float mx = fmaxf(fmaxf(acc[0][i][j][r], acc[1][i][j][r]),
                                 fmaxf(acc[2][i][j][r], acc[3][i][j][r]));
                u[r] = f2bf(fmaxf(mx + bias[oc_l + r], 0.f));
            }
            *(uint2*)(Y + ((size_t)pos * 4096 + n) * 64 + oc_l) = *(const uint2*)u;
        }
    }
}

// ---------------------------------------------------------------------------
// conv3 as LDS-staged GEMM + pool-max (round-9, unchanged).
// ---------------------------------------------------------------------------
template <int IC, int H, int OC, bool FC_EPI, int MINB>
__global__ __launch_bounds__(256, MINB)
void conv_gemm(const ushort_t* __restrict__ X, const ushort_t* __restrict__ WT,
               const float* __restrict__ bias, ushort_t* __restrict__ Y) {
    constexpr int PW = H / 2;
    constexpr int K  = 9 * IC;
    constexpr int CH = IC / 8;
    constexpr int CM = CH - 1;
    constexpr int KK = IC / 32;
    constexpr int WM = (OC == 128) ? 2 : 1;
    constexpr int WN = 4 / WM;
    constexpr int WTM = OC / WM / 16;
    constexpr int WTN = 128 / WN / 16;
    constexpr int APASS = OC * CH / 256;
    constexpr int BPASS = 128 * CH / 256;
    constexpr int NPOS = PW * PW;

    __shared__ ushort_t As[OC * IC];
    __shared__ ushort_t Bs[128 * IC];
    const int tid = threadIdx.x;
    const int wid = tid >> 6, lane = tid & 63;
    const int wm = wid / WN, wn = wid % WN;
    const int l15 = lane & 15, l4 = lane >> 4;
    const int orig = blockIdx.x;
    const int nwg = NPOS * 32;
    const int lin = (orig & 7) * (nwg / 8) + (orig >> 3);
    const int ph = (lin % NPOS) / PW, pw = (lin % NPOS) % PW;
    const int n0 = (lin / NPOS) * 128;

    f32x4 acc[WTM][WTN], mx[WTM][WTN];

    for (int p = 0; p < 4; ++p) {
#pragma unroll
        for (int i = 0; i < WTM; ++i)
#pragma unroll
            for (int j = 0; j < WTN; ++j)
#pragma unroll
                for (int r = 0; r < 4; ++r) acc[i][j][r] = 0.f;
        const int pr = p >> 1, pc = p & 1;
        for (int t = 0; t < 9; ++t) {
            const int kh = t / 3, kw = t % 3;
            const int ih = 2 * ph + pr - 1 + kh;
            const int iw = 2 * pw + pc - 1 + kw;
            if ((unsigned)ih >= (unsigned)H || (unsigned)iw >= (unsigned)H) continue;
            __syncthreads();
            const ushort_t* bsrc = X + (size_t)(ih * H + iw) * 4096 * IC + (size_t)n0 * IC;
#pragma unroll
            for (int pass = 0; pass < APASS; ++pass) {
                int idx = pass * 256 + tid;
                int m = idx / CH, ss = idx % CH;
                int cc = ss ^ (m & CM);
                gload_lds16(WT + (size_t)m * K + t * IC + cc * 8,
                            &As[(pass * 256 + wid * 64) * 8]);
            }
#pragma unroll
            for (int pass = 0; pass < BPASS; ++pass) {
                int idx = pass * 256 + tid;
                int m = idx / CH, ss = idx % CH;
                int cc = ss ^ (m & CM);
                gload_lds16(bsrc + (size_t)m * IC + cc * 8,
                            &Bs[(pass * 256 + wid * 64) * 8]);
            }
            __syncthreads();
#pragma unroll
            for (int kk = 0; kk < KK; ++kk) {
                short8 af[WTM], bf[WTN];
                int c = kk * 4 + l4;
#pragma unroll
                for (int i = 0; i < WTM; ++i) {
                    int m = wm * (WTM * 16) + i * 16 + l15;
                    af[i] = *(const short8*)(As + m * IC + ((c ^ (m & CM)) * 8));
                }
#pragma unroll
                for (int j = 0; j < WTN; ++j) {
                    int m = wn * (WTN * 16) + j * 16 + l15;
                    bf[j] = *(const short8*)(Bs + m * IC + ((c ^ (m & CM)) * 8));
                }
#pragma unroll
                for (int i = 0; i < WTM; ++i)
#pragma unroll
                    for (int j = 0; j < WTN; ++j)
                        acc[i][j] = __builtin_amdgcn_mfma_f32_16x16x32_bf16(
                            af[i], bf[j], acc[i][j], 0, 0, 0);
            }
        }
#pragma unroll
        for (int i = 0; i < WTM; ++i)
#pragma unroll
            for (int j = 0; j < WTN; ++j)
#pragma unroll
                for (int r = 0; r < 4; ++r)
                    mx[i][j][r] = (p == 0) ? acc[i][j][r]
                                           : fmaxf(mx[i][j][r], acc[i][j][r]);
    }

#pragma unroll
    for (int i = 0; i < WTM; ++i) {
        int oc_l = wm * (WTM * 16) + i * 16 + l4 * 4;
#pragma unroll
        for (int j = 0; j < WTN; ++j) {
            int n = n0 + wn * (WTN * 16) + j * 16 + l15;
            ushort_t u[4];
#pragma unroll
            for (int r = 0; r < 4; ++r)
                u[r] = f2bf(fmaxf(mx[i][j][r] + bias[oc_l + r], 0.f));
            if (FC_EPI)
                *(uint2*)(Y + (size_t)n * 2048 + (ph * 4 + pw) * 128 + oc_l) = *(const uint2*)u;
            else
                *(uint2*)(Y + ((size_t)(ph * PW + pw) * 4096 + n) * OC + oc_l) = *(const uint2*)u;
        }
    }
}

// ---------------------------------------------------------------------------
// FC GEMM with 2-phase double-buffer: stage k-step t+1 while computing t.
// 128x128 tile, BK=64, 4 waves, mfma 16x16x32, stage_rc XOR swizzle.
// ---------------------------------------------------------------------------
template <bool RELU, bool F32OUT>
__global__ __launch_bounds__(256, 2)
void fc_mfma(const ushort_t* __restrict__ A, const ushort_t* __restrict__ BT,
             const float* __restrict__ bias, void* __restrict__ Cout,
             int M, int N, int K) {
    __shared__ ushort_t As[2][128 * 64];
    __shared__ ushort_t Bs[2][128 * 64];
    const int tid = threadIdx.x;
    const int wid = tid >> 6, lane = tid & 63;
    const int wr = wid >> 1, wc = wid & 1;
    const int tm = blockIdx.y * 128, tn = blockIdx.x * 128;
    const int l15 = lane & 15, l4 = lane >> 4;

    f32x4 acc[4][4];
#pragma unroll
    for (int i = 0; i < 4; ++i)
#pragma unroll
        for (int j = 0; j < 4; ++j)
#pragma unroll
            for (int r = 0; r < 4; ++r) acc[i][j][r] = 0.f;

    const int NT = K >> 6;
    // prologue: stage k-step 0 into buffer 0
#pragma unroll
    for (int pass = 0; pass < 4; ++pass) {
        int m = pass * 32 + (tid >> 3);
        int cc = (tid & 7) ^ (m & 7);
        gload_lds16(A  + (size_t)(tm + m) * K + cc * 8,
                    &As[0][(pass * 256 + wid * 64) * 8]);
        gload_lds16(BT + (size_t)(tn + m) * K + cc * 8,
                    &Bs[0][(pass * 256 + wid * 64) * 8]);
    }
    __syncthreads();

    for (int t = 0; t < NT; ++t) {
        const int cur = t & 1, nxt = cur ^ 1;
        if (t + 1 < NT) {
            const int k1 = (t + 1) << 6;
#pragma unroll
            for (int pass = 0; pass < 4; ++pass) {
                int m = pass * 32 + (tid >> 3);
                int cc = (tid & 7) ^ (m & 7);
                gload_lds16(A  + (size_t)(tm + m) * K + k1 + cc * 8,
                            &As[nxt][(pass * 256 + wid * 64) * 8]);
                gload_lds16(BT + (size_t)(tn + m) * K + k1 + cc * 8,
                            &Bs[nxt][(pass * 256 + wid * 64) * 8]);
            }
        }
#pragma unroll
        for (int kk = 0; kk < 2; ++kk) {
            short8 af[4], bfr[4];
            int c = kk * 4 + l4;
#pragma unroll
            for (int i = 0; i < 4; ++i) {
                int m = wr * 64 + i * 16 + l15;
                af[i]  = *(const short8*)(&As[cur][m * 64 + (c ^ (m & 7)) * 8]);
                int nn = wc * 64 + i * 16 + l15;
                bfr[i] = *(const short8*)(&Bs[cur][nn * 64 + (c ^ (nn & 7)) * 8]);
            }
#pragma unroll
            for (int i = 0; i < 4; ++i)
#pragma unroll
                for (int j = 0; j < 4; ++j)
                    acc[i][j] = __builtin_amdgcn_mfma_f32_16x16x32_bf16(
                        af[i], bfr[j], acc[i][j], 0, 0, 0);
        }
        __syncthreads();
    }

#pragma unroll
    for (int i = 0; i < 4; ++i) {
        int row = tm + wr * 64 + i * 16 + l4 * 4;
#pragma unroll
        for (int j = 0; j < 4; ++j) {
            int col = tn + wc * 64 + j * 16 + l15;
            float bv = bias[col];
#pragma unroll
            for (int r = 0; r < 4; ++r) {
                float v = acc[i][j][r] + bv;
                if (RELU) v = fmaxf(v, 0.f);
                if (F32OUT)
                    ((float*)Cout)[(size_t)(row + r) * N + col] = v;
                else
                    ((ushort_t*)Cout)[(size_t)(row + r) * N + col] = f2bf(v);
            }
        }
    }
}

// ---------------------------------------------------------------------------
extern "C" void kernel_launch(void* const* d_in, const int* in_sizes, int n_in,
                              void* d_out, int out_size, void* d_ws, size_t ws_size,
                              hipStream_t stream) {
    const float* x     = (const float*)d_in[0];
    const float* noise = (const float*)d_in[1];
    const float* c1w = (const float*)d_in[2];  const float* c1b = (const float*)d_in[3];
    const float* c2w = (const float*)d_in[4];  const float* c2b = (const float*)d_in[5];
    const float* c3w = (const float*)d_in[6];  const float* c3b = (const float*)d_in[7];
    const float* f1w = (const float*)d_in[8];  const float* f1b = (const float*)d_in[9];
    const float* f2w = (const float*)d_in[10]; const float* f2b = (const float*)d_in[11];
    const float* f3w = (const float*)d_in[12]; const float* f3b = (const float*)d_in[13];
    const float* f4w = (const float*)d_in[14]; const float* f4b = (const float*)d_in[15];
    const float* f5w = (const float*)d_in[16]; const float* f5b = (const float*)d_in[17];
    float* out = (float*)d_out;

    char* ws = (char*)d_ws;
    const size_t MB = 1ull << 20;
    int*      ids  = (int*)ws;                               // 256 KB
    ushort_t* wc1  = (ushort_t*)(ws + 1 * MB);               // 6 KB
    ushort_t* wc2  = (ushort_t*)(ws + 1 * MB + 64 * 1024);   // 36 KB
    ushort_t* wc3  = (ushort_t*)(ws + 1 * MB + 128 * 1024);  // 144 KB
    ushort_t* wf1  = (ushort_t*)(ws + 2 * MB);               // 4 MB
    ushort_t* wf2  = (ushort_t*)(ws + 6 * MB);               // 2 MB
    ushort_t* wf3  = (ushort_t*)(ws + 8 * MB);               // 2 MB
    ushort_t* wf4  = (ushort_t*)(ws + 10 * MB);              // 2 MB
    ushort_t* wf5  = (ushort_t*)(ws + 12 * MB);              // 0.5 MB
    ushort_t* act0 = (ushort_t*)(ws + 13 * MB);              // 75.5 MB [32][36][4096][8]
    ushort_t* act1 = (ushort_t*)(ws + 89 * MB);              // 64 MB  [16][16][4096][32]
    ushort_t* act2 = (ushort_t*)(ws + 153 * MB);             // 32 MB  [8][8][4096][64]
    ushort_t* act3 = (ushort_t*)(ws + 185 * MB);             // 16 MB  [4096][2048]
    ushort_t* fcb1 = (ushort_t*)(ws + 201 * MB);             // 8 MB
    ushort_t* fcb2 = (ushort_t*)(ws + 209 * MB);             // 8 MB

    // weight preps
    prep_convw<<<(32 * 96 + 255) / 256, 256, 0, stream>>>(c1w, wc1, 32, 3, 8, 4);
    prep_convw<<<(64 * 288 + 255) / 256, 256, 0, stream>>>(c2w, wc2, 64, 32, 32, 3);
    prep_convw<<<(128 * 576 + 255) / 256, 256, 0, stream>>>(c3w, wc3, 128, 64, 64, 3);
    transpose_w_fc1<<<dim3(64, 32), 256, 0, stream>>>(f1w, wf1);
    transpose_w<<<dim3(32, 32), 256, 0, stream>>>(f2w, wf2, 1024, 1024);
    transpose_w<<<dim3(32, 32), 256, 0, stream>>>(f3w, wf3, 1024, 1024);
    transpose_w<<<dim3(32, 32), 256, 0, stream>>>(f4w, wf4, 1024, 1024);
    transpose_w<<<dim3(32, 8),  256, 0, stream>>>(f5w, wf5, 1024, 256);

    // shuffle + target
    rank_kernel<<<BATCH / 256, 256, 0, stream>>>(noise, ids, out + (size_t)BATCH * 256);
    shuffle_transpose<<<dim3(32, 64), 256, 0, stream>>>(x, ids, act0);

    // convs
    conv1_mfma<<<dim3(256, 64), 256, 0, stream>>>(act0, wc1, c1b, act1);
    conv2_gemm<<<dim3(4096), 256, 0, stream>>>(act1, wc2, c2b, act2);
    conv_gemm<64, 8, 128, true, 2><<<dim3(512), 256, 0, stream>>>(act2, wc3, c3b, act3);

    // FC chain
    fc_mfma<true,  false><<<dim3(8, 32), 256, 0, stream>>>(act3, wf1, f1b, fcb1, BATCH, 1024, 2048);
    fc_mfma<true,  false><<<dim3(8, 32), 256, 0, stream>>>(fcb1, wf2, f2b, fcb2, BATCH, 1024, 1024);
    fc_mfma<true,  false><<<dim3(8, 32), 256, 0, stream>>>(fcb2, wf3, f3b, fcb1, BATCH, 1024, 1024);
    fc_mfma<true,  false><<<dim3(8, 32), 256, 0, stream>>>(fcb1, wf4, f4b, fcb2, BATCH, 1024, 1024);
    fc_mfma<false, true ><<<dim3(2, 32), 256, 0, stream>>>(fcb2, wf5, f5b, out, BATCH, 256, 1024);
}

// Round 11
// 305.178 us; speedup vs baseline: 1.7187x; 1.0449x over previous
//
#include <hip/hip_runtime.h>

#define BATCH 4096
#define NPATCH 16

typedef __attribute__((ext_vector_type(8)))  short  short8;
typedef __attribute__((ext_vector_type(4)))  float  f32x4;
typedef __attribute__((ext_vector_type(16))) float  f32x16;
typedef unsigned short ushort_t;

__device__ __forceinline__ ushort_t f2bf(float f) {
    union { float f; unsigned u; } x; x.f = f;
    unsigned r = x.u + 0x7FFFu + ((x.u >> 16) & 1u);
    return (ushort_t)(r >> 16);
}

__device__ __forceinline__ void gload_lds16(const void* g, void* l) {
    __builtin_amdgcn_global_load_lds((const __attribute__((address_space(1))) void*)g,
                                     (__attribute__((address_space(3))) void*)l, 16, 0, 0);
}

// ---------------------------------------------------------------------------
// rank: ids_shuffle (ws) + ids_restore -> target (f32, d_out tail)
// ---------------------------------------------------------------------------
__global__ void rank_kernel(const float* __restrict__ noise,
                            int* __restrict__ ids_shuffle,
                            float* __restrict__ target_out) {
    int n = blockIdx.x * 256 + threadIdx.x;
    if (n >= BATCH) return;
    float v[NPATCH];
#pragma unroll
    for (int i = 0; i < NPATCH; i++) v[i] = noise[n * NPATCH + i];
#pragma unroll
    for (int j = 0; j < NPATCH; j++) {
        int r = 0;
#pragma unroll
        for (int i = 0; i < NPATCH; i++)
            if (v[i] < v[j] || (v[i] == v[j] && i < j)) r++;
        ids_shuffle[n * NPATCH + r] = j;
        target_out[n * NPATCH + j] = (float)r;
    }
}

// ---------------------------------------------------------------------------
// patch-shuffle + transpose, f32 NCHW -> bf16 [32h][36wpad][4096n][8icpad]
// ---------------------------------------------------------------------------
__global__ void shuffle_transpose(const float* __restrict__ x,
                                  const int* __restrict__ ids,
                                  ushort_t* __restrict__ y) {
    __shared__ float tile[3][64][33];
    int h = blockIdx.x;
    int n0 = blockIdx.y << 6;
    int t = threadIdx.x;
    int w = t & 31;
    int jrow = (h >> 3) << 2;
#pragma unroll
    for (int r = 0; r < 8; r++) {
        int nl = (t >> 5) + (r << 3);
        int n = n0 + nl;
        int j = jrow + (w >> 3);
        int p = ids[(n << 4) + j];
        int sh = ((p >> 2) << 3) | (h & 7);
        int sw = ((p & 3) << 3) | (w & 7);
#pragma unroll
        for (int c = 0; c < 3; c++)
            tile[c][nl][w] = x[n * 3072 + (c << 10) + (sh << 5) + sw];
    }
    __syncthreads();
    int sub = t >> 6, nl = t & 63;
    int n = n0 + nl;
#pragma unroll
    for (int q = 0; q < 9; q++) {
        int wp = sub * 9 + q;            // 0..35
        int iw = wp - 1;
        ushort_t u[8];
#pragma unroll
        for (int e = 0; e < 8; e++) {
            float v = (e < 3 && iw >= 0 && iw < 32) ? tile[e][nl][iw] : 0.f;
            u[e] = f2bf(v);
        }
        *(uint4*)(y + ((size_t)(h * 36 + wp) * 4096 + n) * 8) = *(const uint4*)u;
    }
}

// ---------------------------------------------------------------------------
// conv weight prep: OIHW f32 -> [oc][k] bf16, k = kh*(KWP*ICP)+kw*ICP+ic
// ---------------------------------------------------------------------------
__global__ void prep_convw(const float* __restrict__ W, ushort_t* __restrict__ WT,
                           int OC, int IC, int ICP, int KWP) {
    int KP = 3 * KWP * ICP;
    int i = blockIdx.x * 256 + threadIdx.x;
    if (i >= OC * KP) return;
    int oc = i / KP, k = i % KP;
    int kh = k / (KWP * ICP);
    int kw = (k / ICP) % KWP;
    int ic = k % ICP;
    ushort_t v = 0;
    if (kw < 3 && ic < IC)
        v = f2bf(W[((oc * IC + ic) * 3 + kh) * 3 + kw]);
    WT[i] = v;
}

// ---------------------------------------------------------------------------
// FC weight prep: [K][N] f32 -> [N][K] bf16
// ---------------------------------------------------------------------------
__global__ void transpose_w(const float* __restrict__ W, ushort_t* __restrict__ WT,
                            int K, int N) {
    __shared__ ushort_t t[32][33];
    int kb = blockIdx.x * 32, nb = blockIdx.y * 32;
    int tx = threadIdx.x & 31, ty = threadIdx.x >> 5;
#pragma unroll
    for (int i = 0; i < 32; i += 8)
        t[ty + i][tx] = f2bf(W[(size_t)(kb + ty + i) * N + nb + tx]);
    __syncthreads();
#pragma unroll
    for (int i = 0; i < 32; i += 8)
        WT[(size_t)(nb + ty + i) * K + kb + tx] = t[tx][ty + i];
}

// fc1 weights with permuted k: WT[n][k'] = W[k][n], k' = hw*128+c, k = c*16+hw
__global__ void transpose_w_fc1(const float* __restrict__ W, ushort_t* __restrict__ WT) {
    __shared__ ushort_t t[32][33];
    int kb = blockIdx.x * 32, nb = blockIdx.y * 32;
    int hw = kb >> 7, c0 = kb & 127;
    int tx = threadIdx.x & 31, ty = threadIdx.x >> 5;
#pragma unroll
    for (int i = 0; i < 32; i += 8)
        t[ty + i][tx] = f2bf(W[(size_t)((c0 + ty + i) * 16 + hw) * 1024 + nb + tx]);
    __syncthreads();
#pragma unroll
    for (int i = 0; i < 32; i += 8)
        WT[(size_t)(nb + ty + i) * 2048 + kb + tx] = t[tx][ty + i];
}

// ---------------------------------------------------------------------------
// conv1 v2: 3->32 + relu + pool via mfma 16x16x32 (round-10, unchanged).
// ---------------------------------------------------------------------------
__global__ __launch_bounds__(256, 4)
void conv1_mfma(const ushort_t* __restrict__ X, const ushort_t* __restrict__ WT,
                const float* __restrict__ bias, ushort_t* __restrict__ Y) {
    const int tid = threadIdx.x;
    const int wid = tid >> 6, lane = tid & 63;
    const int l15 = lane & 15, l4 = lane >> 4;
    const int pos = blockIdx.x;
    const int ph = pos >> 4, pw = pos & 15;
    const int n = (blockIdx.y << 6) + (wid << 4) + l15;

    short8 af[3][2];
#pragma unroll
    for (int kh = 0; kh < 3; ++kh)
#pragma unroll
        for (int i = 0; i < 2; ++i)
            af[kh][i] = *(const short8*)(WT + (i * 16 + l15) * 96 + kh * 32 + l4 * 8);

    f32x4 acc[2][4];
#pragma unroll
    for (int i = 0; i < 2; ++i)
#pragma unroll
        for (int p = 0; p < 4; ++p)
#pragma unroll
            for (int r = 0; r < 4; ++r) acc[i][p][r] = 0.f;

#pragma unroll
    for (int pc = 0; pc < 2; ++pc)
#pragma unroll
        for (int rr = 0; rr < 4; ++rr) {
            int ih = 2 * ph - 1 + rr;
            if ((unsigned)ih >= 32u) continue;
            short8 bf = *(const short8*)(
                X + ((size_t)(ih * 36 + 2 * pw + pc + l4) * 4096 + n) * 8);
#pragma unroll
            for (int pr = 0; pr < 2; ++pr) {
                int kh = rr - pr;
                if (kh < 0 || kh > 2) continue;
#pragma unroll
                for (int i = 0; i < 2; ++i)
                    acc[i][pr * 2 + pc] = __builtin_amdgcn_mfma_f32_16x16x32_bf16(
                        af[kh][i], bf, acc[i][pr * 2 + pc], 0, 0, 0);
            }
        }

#pragma unroll
    for (int i = 0; i < 2; ++i) {
        int ocb = i * 16 + l4 * 4;
        ushort_t u[4];
#pragma unroll
        for (int r = 0; r < 4; ++r) {
            float mx = fmaxf(fmaxf(acc[i][0][r], acc[i][1][r]),
                             fmaxf(acc[i][2][r], acc[i][3][r]));
            u[r] = f2bf(fmaxf(mx + bias[ocb + r], 0.f));
        }
        *(uint2*)(Y + ((size_t)pos * 4096 + n) * 32 + ocb) = *(const uint2*)u;
    }
}

// ---------------------------------------------------------------------------
// conv2 v3: row-phase GEMM. Block = 1 pooled pos x 64 n x 64 oc.
// Weights [64][288] resident (36 KB). Input staged a full window ROW at a
// time (4 iw-slabs = 16 KB, double-buffered) -> 5 barriers/block, ~36 MFMAs
// per phase overlapped with next-row staging.
// ---------------------------------------------------------------------------
__global__ __launch_bounds__(256, 2)
void conv2_gemm(const ushort_t* __restrict__ X, const ushort_t* __restrict__ WT,
                const float* __restrict__ bias, ushort_t* __restrict__ Y) {
    __shared__ ushort_t As[64 * 288];        // 36 KB, resident
    __shared__ ushort_t Bs[2][4 * 64 * 32];  // 2 x 16 KB: [iw-slab][64n][32ic]
    const int tid = threadIdx.x;
    const int wid = tid >> 6, lane = tid & 63;
    const int l15 = lane & 15, l4 = lane >> 4;
    const int wm = wid >> 1, wn = wid & 1;
    const int orig = blockIdx.x;
    const int lin = (orig & 7) * 512 + (orig >> 3);
    const int pos = lin & 63;
    const int n0 = (lin >> 6) * 64;
    const int ph = pos >> 3, pw = pos & 7;

    f32x4 acc[4][2][2];
#pragma unroll
    for (int p = 0; p < 4; ++p)
#pragma unroll
        for (int i = 0; i < 2; ++i)
#pragma unroll
            for (int j = 0; j < 2; ++j)
#pragma unroll
                for (int r = 0; r < 4; ++r) acc[p][i][j][r] = 0.f;

    // weights resident (9 passes)
#pragma unroll
    for (int pass = 0; pass < 9; ++pass) {
        int idx = pass * 256 + tid;
        int m = idx / 36, ss = idx % 36;
        int cc = ss ^ ((m >> 1) & 3);
        gload_lds16(WT + (size_t)m * 288 + cc * 8, &As[(pass * 256 + wid * 64) * 8]);
    }
    // stage row 0 (ih = 2ph-1) into buf 0
    {
        int ih = 2 * ph - 1;
        if (ih >= 0) {
#pragma unroll
            for (int dw = 0; dw < 4; ++dw) {
                int iw = 2 * pw - 1 + dw;
                if ((unsigned)iw >= 16u) continue;
                int m = tid >> 2, ss = tid & 3;
                int cc = ss ^ ((m >> 1) & 3);
                gload_lds16(X + ((size_t)(ih * 16 + iw) * 4096 + n0 + m) * 32 + cc * 8,
                            &Bs[0][dw * 2048 + wid * 512]);
            }
        }
    }
    __syncthreads();

#pragma unroll
    for (int r = 0; r < 4; ++r) {
        const int cur = r & 1;
        // prefetch next row into the other buffer
        if (r < 3) {
            int ihn = 2 * ph + r;           // row r+1
            if (ihn < 16) {
#pragma unroll
                for (int dw = 0; dw < 4; ++dw) {
                    int iw = 2 * pw - 1 + dw;
                    if ((unsigned)iw >= 16u) continue;
                    int m = tid >> 2, ss = tid & 3;
                    int cc = ss ^ ((m >> 1) & 3);
                    gload_lds16(X + ((size_t)(ihn * 16 + iw) * 4096 + n0 + m) * 32 + cc * 8,
                                &Bs[cur ^ 1][dw * 2048 + wid * 512]);
                }
            }
        }
        // compute current row
        int ih = 2 * ph - 1 + r;
        if ((unsigned)ih < 16u) {
            short8 bf[4][2];
#pragma unroll
            for (int dw = 0; dw < 4; ++dw)
#pragma unroll
                for (int j = 0; j < 2; ++j) {
                    int m2 = wn * 32 + j * 16 + l15;
                    bf[dw][j] = *(const short8*)(
                        &Bs[cur][(dw * 64 + m2) * 32 + ((l4 ^ ((m2 >> 1) & 3)) * 8)]);
                }
#pragma unroll
            for (int pr = 0; pr < 2; ++pr) {
                int kh = r - pr;
                if (kh < 0 || kh > 2) continue;
#pragma unroll
                for (int pc = 0; pc < 2; ++pc)
#pragma unroll
                    for (int kw = 0; kw < 3; ++kw) {
                        int dw = kw + pc;
                        int iw = 2 * pw - 1 + dw;
                        if ((unsigned)iw >= 16u) continue;
                        int tap = kh * 3 + kw;
                        short8 af[2];
#pragma unroll
                        for (int i = 0; i < 2; ++i) {
                            int m = wm * 32 + i * 16 + l15;
                            int g = tap * 4 + l4;
                            af[i] = *(const short8*)(
                                &As[m * 288 + ((g ^ ((m >> 1) & 3)) * 8)]);
                        }
#pragma unroll
                        for (int i = 0; i < 2; ++i)
#pragma unroll
                            for (int j = 0; j < 2; ++j)
                                acc[pr * 2 + pc][i][j] =
                                    __builtin_amdgcn_mfma_f32_16x16x32_bf16(
                                        af[i], bf[dw][j], acc[pr * 2 + pc][i][j], 0, 0, 0);
                    }
            }
        }
        __syncthreads();
    }

    // pool-max + bias + relu; write [pos][4096n][64oc]
#pragma unroll
    for (int i = 0; i < 2; ++i) {
        int oc_l = wm * 32 + i * 16 + l4 * 4;
#pragma unroll
        for (int j = 0; j < 2; ++j) {
            int n = n0 + wn * 32 + j * 16 + l15;
            ushort_t u[4];
#pragma unroll
            for (int r = 0; r < 4; ++r) {
                float mx = fmaxf(fmaxf(acc[0][i][j][r], acc[1][i][j][r]),
                                 fmaxf(acc[2][i][j][r], acc[3][i][j][r]));
                u[r] = f2bf(fmaxf(mx + bias[oc_l + r], 0.f));
            }
            *(uint2*)(Y + ((size_t)pos * 4096 + n) * 64 + oc_l) = *(const uint2*)u;
        }
    }
}

// ---------------------------------------------------------------------------
// conv3 as LDS-staged GEMM + pool-max (round-9, unchanged).
// ---------------------------------------------------------------------------
template <int IC, int H, int OC, bool FC_EPI, int MINB>
__global__ __launch_bounds__(256, MINB)
void conv_gemm(const ushort_t* __restrict__ X, const ushort_t* __restrict__ WT,
               const float* __restrict__ bias, ushort_t* __restrict__ Y) {
    constexpr int PW = H / 2;
    constexpr int K  = 9 * IC;
    constexpr int CH = IC / 8;
    constexpr int CM = CH - 1;
    constexpr int KK = IC / 32;
    constexpr int WM = (OC == 128) ? 2 : 1;
    constexpr int WN = 4 / WM;
    constexpr int WTM = OC / WM / 16;
    constexpr int WTN = 128 / WN / 16;
    constexpr int APASS = OC * CH / 256;
    constexpr int BPASS = 128 * CH / 256;
    constexpr int NPOS = PW * PW;

    __shared__ ushort_t As[OC * IC];
    __shared__ ushort_t Bs[128 * IC];
    const int tid = threadIdx.x;
    const int wid = tid >> 6, lane = tid & 63;
    const int wm = wid / WN, wn = wid % WN;
    const int l15 = lane & 15, l4 = lane >> 4;
    const int orig = blockIdx.x;
    const int nwg = NPOS * 32;
    const int lin = (orig & 7) * (nwg / 8) + (orig >> 3);
    const int ph = (lin % NPOS) / PW, pw = (lin % NPOS) % PW;
    const int n0 = (lin / NPOS) * 128;

    f32x4 acc[WTM][WTN], mx[WTM][WTN];

    for (int p = 0; p < 4; ++p) {
#pragma unroll
        for (int i = 0; i < WTM; ++i)
#pragma unroll
            for (int j = 0; j < WTN; ++j)
#pragma unroll
                for (int r = 0; r < 4; ++r) acc[i][j][r] = 0.f;
        const int pr = p >> 1, pc = p & 1;
        for (int t = 0; t < 9; ++t) {
            const int kh = t / 3, kw = t % 3;
            const int ih = 2 * ph + pr - 1 + kh;
            const int iw = 2 * pw + pc - 1 + kw;
            if ((unsigned)ih >= (unsigned)H || (unsigned)iw >= (unsigned)H) continue;
            __syncthreads();
            const ushort_t* bsrc = X + (size_t)(ih * H + iw) * 4096 * IC + (size_t)n0 * IC;
#pragma unroll
            for (int pass = 0; pass < APASS; ++pass) {
                int idx = pass * 256 + tid;
                int m = idx / CH, ss = idx % CH;
                int cc = ss ^ (m & CM);
                gload_lds16(WT + (size_t)m * K + t * IC + cc * 8,
                            &As[(pass * 256 + wid * 64) * 8]);
            }
#pragma unroll
            for (int pass = 0; pass < BPASS; ++pass) {
                int idx = pass * 256 + tid;
                int m = idx / CH, ss = idx % CH;
                int cc = ss ^ (m & CM);
                gload_lds16(bsrc + (size_t)m * IC + cc * 8,
                            &Bs[(pass * 256 + wid * 64) * 8]);
            }
            __syncthreads();
#pragma unroll
            for (int kk = 0; kk < KK; ++kk) {
                short8 af[WTM], bf[WTN];
                int c = kk * 4 + l4;
#pragma unroll
                for (int i = 0; i < WTM; ++i) {
                    int m = wm * (WTM * 16) + i * 16 + l15;
                    af[i] = *(const short8*)(As + m * IC + ((c ^ (m & CM)) * 8));
                }
#pragma unroll
                for (int j = 0; j < WTN; ++j) {
                    int m = wn * (WTN * 16) + j * 16 + l15;
                    bf[j] = *(const short8*)(Bs + m * IC + ((c ^ (m & CM)) * 8));
                }
#pragma unroll
                for (int i = 0; i < WTM; ++i)
#pragma unroll
                    for (int j = 0; j < WTN; ++j)
                        acc[i][j] = __builtin_amdgcn_mfma_f32_16x16x32_bf16(
                            af[i], bf[j], acc[i][j], 0, 0, 0);
            }
        }
#pragma unroll
        for (int i = 0; i < WTM; ++i)
#pragma unroll
            for (int j = 0; j < WTN; ++j)
#pragma unroll
                for (int r = 0; r < 4; ++r)
                    mx[i][j][r] = (p == 0) ? acc[i][j][r]
                                           : fmaxf(mx[i][j][r], acc[i][j][r]);
    }

#pragma unroll
    for (int i = 0; i < WTM; ++i) {
        int oc_l = wm * (WTM * 16) + i * 16 + l4 * 4;
#pragma unroll
        for (int j = 0; j < WTN; ++j) {
            int n = n0 + wn * (WTN * 16) + j * 16 + l15;
            ushort_t u[4];
#pragma unroll
            for (int r = 0; r < 4; ++r)
                u[r] = f2bf(fmaxf(mx[i][j][r] + bias[oc_l + r], 0.f));
            if (FC_EPI)
                *(uint2*)(Y + (size_t)n * 2048 + (ph * 4 + pw) * 128 + oc_l) = *(const uint2*)u;
            else
                *(uint2*)(Y + ((size_t)(ph * PW + pw) * 4096 + n) * OC + oc_l) = *(const uint2*)u;
        }
    }
}

// ---------------------------------------------------------------------------
// FC GEMM: 128M x 64N tile, BK=64, dbuf -> 48 KB LDS, grid 512 = 2 blocks/CU.
// 4 waves as 2(row)x2(col); mfma 16x16x32; stage_rc XOR swizzle.
// ---------------------------------------------------------------------------
template <bool RELU, bool F32OUT>
__global__ __launch_bounds__(256, 2)
void fc_mfma(const ushort_t* __restrict__ A, const ushort_t* __restrict__ BT,
             const float* __restrict__ bias, void* __restrict__ Cout,
             int M, int N, int K) {
    __shared__ ushort_t As[2][128 * 64];   // 2 x 16 KB
    __shared__ ushort_t Bs[2][64 * 64];    // 2 x  8 KB
    const int tid = threadIdx.x;
    const int wid = tid >> 6, lane = tid & 63;
    const int wr = wid >> 1, wc = wid & 1;
    const int tm = blockIdx.y * 128, tn = blockIdx.x * 64;
    const int l15 = lane & 15, l4 = lane >> 4;

    f32x4 acc[4][2];
#pragma unroll
    for (int i = 0; i < 4; ++i)
#pragma unroll
        for (int j = 0; j < 2; ++j)
#pragma unroll
            for (int r = 0; r < 4; ++r) acc[i][j][r] = 0.f;

    const int NT = K >> 6;
    // prologue: stage k-step 0
#pragma unroll
    for (int pass = 0; pass < 4; ++pass) {
        int m = pass * 32 + (tid >> 3);
        int cc = (tid & 7) ^ (m & 7);
        gload_lds16(A + (size_t)(tm + m) * K + cc * 8,
                    &As[0][(pass * 256 + wid * 64) * 8]);
    }
#pragma unroll
    for (int pass = 0; pass < 2; ++pass) {
        int m = pass * 32 + (tid >> 3);
        int cc = (tid & 7) ^ (m & 7);
        gload_lds16(BT + (size_t)(tn + m) * K + cc * 8,
                    &Bs[0][(pass * 256 + wid * 64) * 8]);
    }
    __syncthreads();

    for (int t = 0; t < NT; ++t) {
        const int cur = t & 1, nxt = cur ^ 1;
        if (t + 1 < NT) {
            const int k1 = (t + 1) << 6;
#pragma unroll
            for (int pass = 0; pass < 4; ++pass) {
                int m = pass * 32 + (tid >> 3);
                int cc = (tid & 7) ^ (m & 7);
                gload_lds16(A + (size_t)(tm + m) * K + k1 + cc * 8,
                            &As[nxt][(pass * 256 + wid * 64) * 8]);
            }
#pragma unroll
            for (int pass = 0; pass < 2; ++pass) {
                int m = pass * 32 + (tid >> 3);
                int cc = (tid & 7) ^ (m & 7);
                gload_lds16(BT + (size_t)(tn + m) * K + k1 + cc * 8,
                            &Bs[nxt][(pass * 256 + wid * 64) * 8]);
            }
        }
#pragma unroll
        for (int kk = 0; kk < 2; ++kk) {
            short8 af[4], bfr[2];
            int c = kk * 4 + l4;
#pragma unroll
            for (int i = 0; i < 4; ++i) {
                int m = wr * 64 + i * 16 + l15;
                af[i] = *(const short8*)(&As[cur][m * 64 + (c ^ (m & 7)) * 8]);
            }
#pragma unroll
            for (int j = 0; j < 2; ++j) {
                int nn = wc * 32 + j * 16 + l15;
                bfr[j] = *(const short8*)(&Bs[cur][nn * 64 + (c ^ (nn & 7)) * 8]);
            }
#pragma unroll
            for (int i = 0; i < 4; ++i)
#pragma unroll
                for (int j = 0; j < 2; ++j)
                    acc[i][j] = __builtin_amdgcn_mfma_f32_16x16x32_bf16(
                        af[i], bfr[j], acc[i][j], 0, 0, 0);
        }
        __syncthreads();
    }

#pragma unroll
    for (int i = 0; i < 4; ++i) {
        int row = tm + wr * 64 + i * 16 + l4 * 4;
#pragma unroll
        for (int j = 0; j < 2; ++j) {
            int col = tn + wc * 32 + j * 16 + l15;
            float bv = bias[col];
#pragma unroll
            for (int r = 0; r < 4; ++r) {
                float v = acc[i][j][r] + bv;
                if (RELU) v = fmaxf(v, 0.f);
                if (F32OUT)
                    ((float*)Cout)[(size_t)(row + r) * N + col] = v;
                else
                    ((ushort_t*)Cout)[(size_t)(row + r) * N + col] = f2bf(v);
            }
        }
    }
}

// ---------------------------------------------------------------------------
extern "C" void kernel_launch(void* const* d_in, const int* in_sizes, int n_in,
                              void* d_out, int out_size, void* d_ws, size_t ws_size,
                              hipStream_t stream) {
    const float* x     = (const float*)d_in[0];
    const float* noise = (const float*)d_in[1];
    const float* c1w = (const float*)d_in[2];  const float* c1b = (const float*)d_in[3];
    const float* c2w = (const float*)d_in[4];  const float* c2b = (const float*)d_in[5];
    const float* c3w = (const float*)d_in[6];  const float* c3b = (const float*)d_in[7];
    const float* f1w = (const float*)d_in[8];  const float* f1b = (const float*)d_in[9];
    const float* f2w = (const float*)d_in[10]; const float* f2b = (const float*)d_in[11];
    const float* f3w = (const float*)d_in[12]; const float* f3b = (const float*)d_in[13];
    const float* f4w = (const float*)d_in[14]; const float* f4b = (const float*)d_in[15];
    const float* f5w = (const float*)d_in[16]; const float* f5b = (const float*)d_in[17];
    float* out = (float*)d_out;

    char* ws = (char*)d_ws;
    const size_t MB = 1ull << 20;
    int*      ids  = (int*)ws;                               // 256 KB
    ushort_t* wc1  = (ushort_t*)(ws + 1 * MB);               // 6 KB
    ushort_t* wc2  = (ushort_t*)(ws + 1 * MB + 64 * 1024);   // 36 KB
    ushort_t* wc3  = (ushort_t*)(ws + 1 * MB + 128 * 1024);  // 144 KB
    ushort_t* wf1  = (ushort_t*)(ws + 2 * MB);               // 4 MB
    ushort_t* wf2  = (ushort_t*)(ws + 6 * MB);               // 2 MB
    ushort_t* wf3  = (ushort_t*)(ws + 8 * MB);               // 2 MB
    ushort_t* wf4  = (ushort_t*)(ws + 10 * MB);              // 2 MB
    ushort_t* wf5  = (ushort_t*)(ws + 12 * MB);              // 0.5 MB
    ushort_t* act0 = (ushort_t*)(ws + 13 * MB);              // 75.5 MB [32][36][4096][8]
    ushort_t* act1 = (ushort_t*)(ws + 89 * MB);              // 64 MB  [16][16][4096][32]
    ushort_t* act2 = (ushort_t*)(ws + 153 * MB);             // 32 MB  [8][8][4096][64]
    ushort_t* act3 = (ushort_t*)(ws + 185 * MB);             // 16 MB  [4096][2048]
    ushort_t* fcb1 = (ushort_t*)(ws + 201 * MB);             // 8 MB
    ushort_t* fcb2 = (ushort_t*)(ws + 209 * MB);             // 8 MB

    // weight preps
    prep_convw<<<(32 * 96 + 255) / 256, 256, 0, stream>>>(c1w, wc1, 32, 3, 8, 4);
    prep_convw<<<(64 * 288 + 255) / 256, 256, 0, stream>>>(c2w, wc2, 64, 32, 32, 3);
    prep_convw<<<(128 * 576 + 255) / 256, 256, 0, stream>>>(c3w, wc3, 128, 64, 64, 3);
    transpose_w_fc1<<<dim3(64, 32), 256, 0, stream>>>(f1w, wf1);
    transpose_w<<<dim3(32, 32), 256, 0, stream>>>(f2w, wf2, 1024, 1024);
    transpose_w<<<dim3(32, 32), 256, 0, stream>>>(f3w, wf3, 1024, 1024);
    transpose_w<<<dim3(32, 32), 256, 0, stream>>>(f4w, wf4, 1024, 1024);
    transpose_w<<<dim3(32, 8),  256, 0, stream>>>(f5w, wf5, 1024, 256);

    // shuffle + target
    rank_kernel<<<BATCH / 256, 256, 0, stream>>>(noise, ids, out + (size_t)BATCH * 256);
    shuffle_transpose<<<dim3(32, 64), 256, 0, stream>>>(x, ids, act0);

    // convs
    conv1_mfma<<<dim3(256, 64), 256, 0, stream>>>(act0, wc1, c1b, act1);
    conv2_gemm<<<dim3(4096), 256, 0, stream>>>(act1, wc2, c2b, act2);
    conv_gemm<64, 8, 128, true, 2><<<dim3(512), 256, 0, stream>>>(act2, wc3, c3b, act3);

    // FC chain (128x64 tiles, 2 blocks/CU)
    fc_mfma<true,  false><<<dim3(16, 32), 256, 0, stream>>>(act3, wf1, f1b, fcb1, BATCH, 1024, 2048);
    fc_mfma<true,  false><<<dim3(16, 32), 256, 0, stream>>>(fcb1, wf2, f2b, fcb2, BATCH, 1024, 1024);
    fc_mfma<true,  false><<<dim3(16, 32), 256, 0, stream>>>(fcb2, wf3, f3b, fcb1, BATCH, 1024, 1024);
    fc_mfma<true,  false><<<dim3(16, 32), 256, 0, stream>>>(fcb1, wf4, f4b, fcb2, BATCH, 1024, 1024);
    fc_mfma<false, true ><<<dim3(4, 32),  256, 0, stream>>>(fcb2, wf5, f5b, out, BATCH, 256, 1024);
}